// Round 9
// baseline (387.085 us; speedup 1.0000x reference)
//
#include <hip/hip_runtime.h>

#define NN   100000
#define NE   1600000
#define DIN  128
#define DH   64
#define DOUT 128
#define NG   512

#define NB   391     // dst buckets of 256 nodes: ceil(NN/256)
#define EPB  6250    // edges per partition block: NE/256
#define MSZ  (NB*256) // 100,096 — scan length

// ---------- radix pass A1: per-(block,bucket) histogram ----------
__global__ __launch_bounds__(256) void histA_kernel(
    const int* __restrict__ dst, int* __restrict__ cnt) {
  __shared__ int h[NB];
  for (int i = threadIdx.x; i < NB; i += 256) h[i] = 0;
  __syncthreads();
  int start = blockIdx.x * EPB, end = start + EPB;
  for (int e = start + threadIdx.x; e < end; e += 256)
    atomicAdd(&h[dst[e] >> 8], 1);
  __syncthreads();
  for (int b = threadIdx.x; b < NB; b += 256)
    cnt[b * 256 + blockIdx.x] = h[b];   // bucket-major layout
}

// ---------- scan pass 1: per-block sums ----------
__global__ __launch_bounds__(256) void reduce_kernel(
    const int* __restrict__ cnt, int* __restrict__ partials) {
  __shared__ int s[256];
  int i = blockIdx.x * 256 + threadIdx.x;
  s[threadIdx.x] = cnt[i];
  __syncthreads();
  for (int off = 128; off > 0; off >>= 1) {
    if (threadIdx.x < off) s[threadIdx.x] += s[threadIdx.x + off];
    __syncthreads();
  }
  if (threadIdx.x == 0) partials[blockIdx.x] = s[0];
}

// ---------- scan pass 2: exclusive scan of NB partials (1 block) ----------
__global__ __launch_bounds__(256) void scanpart_kernel(int* __restrict__ partials) {
  __shared__ int s[NB];
  for (int i = threadIdx.x; i < NB; i += 256) s[i] = partials[i];
  __syncthreads();
  if (threadIdx.x == 0) {
    int run = 0;
    for (int i = 0; i < NB; ++i) { int v = s[i]; s[i] = run; run += v; }
  }
  __syncthreads();
  for (int i = threadIdx.x; i < NB; i += 256) partials[i] = s[i];
}

// ---------- scan pass 3: per-block exclusive scan + offset ----------
__global__ __launch_bounds__(256) void scanfinal_kernel(
    const int* __restrict__ cnt, const int* __restrict__ partials,
    int* __restrict__ scanned) {
  __shared__ int s[256];
  int t = threadIdx.x;
  int i = blockIdx.x * 256 + t;
  int c = cnt[i];
  s[t] = c;
  __syncthreads();
  for (int off = 1; off < 256; off <<= 1) {
    int v = (t >= off) ? s[t - off] : 0;
    __syncthreads();
    s[t] += v;
    __syncthreads();
  }
  scanned[i] = s[t] - c + partials[blockIdx.x];
}

// ---------- radix pass A2: partition packed edges into buckets ----------
__global__ __launch_bounds__(256) void partA_kernel(
    const int* __restrict__ src, const int* __restrict__ dst,
    const int* __restrict__ scanned, int* __restrict__ part) {
  __shared__ int cur[NB];
  for (int i = threadIdx.x; i < NB; i += 256)
    cur[i] = scanned[i * 256 + blockIdx.x];
  __syncthreads();
  int start = blockIdx.x * EPB, end = start + EPB;
  for (int e = start + threadIdx.x; e < end; e += 256) {
    int d = dst[e], s = src[e];
    int pos = atomicAdd(&cur[d >> 8], 1);
    part[pos] = ((d & 255) << 17) | s;
  }
}

// ---------- radix pass B: per-bucket CSR (row_start + eidx) ----------
__global__ __launch_bounds__(256) void bucket_csr_kernel(
    const int* __restrict__ part, const int* __restrict__ scanned,
    int* __restrict__ row_start, int* __restrict__ eidx) {
  int b = blockIdx.x, t = threadIdx.x;
  int ebeg = scanned[b * 256];
  int eend = (b == NB - 1) ? NE : scanned[(b + 1) * 256];
  int nbase = b << 8;
  int nloc = NN - nbase; if (nloc > 256) nloc = 256;
  __shared__ int cntL[256];
  __shared__ int exclL[256];
  cntL[t] = 0;
  __syncthreads();
  for (int e = ebeg + t; e < eend; e += 256)
    atomicAdd(&cntL[part[e] >> 17], 1);
  __syncthreads();
  int c = cntL[t];
  exclL[t] = c;
  __syncthreads();
  for (int off = 1; off < 256; off <<= 1) {
    int v = (t >= off) ? exclL[t - off] : 0;
    __syncthreads();
    exclL[t] += v;
    __syncthreads();
  }
  int excl = exclL[t] - c;
  if (t < nloc) row_start[nbase + t] = ebeg + excl;
  if (b == NB - 1 && t == 0) row_start[NN] = NE;
  cntL[t] = excl;                 // reuse as cursor
  __syncthreads();
  for (int e = ebeg + t; e < eend; e += 256) {
    int v = part[e];
    int pos = atomicAdd(&cntL[v >> 17], 1);
    eidx[ebeg + pos] = v & 0x1FFFF;
  }
}

// ---------- graph boundaries: batch is sorted -> binary search ----------
__global__ __launch_bounds__(256) void bounds_kernel(
    const int* __restrict__ batch, int* __restrict__ gs) {
  int g = blockIdx.x * 256 + threadIdx.x;
  if (g > NG) return;
  if (g == NG) { gs[NG] = NN; return; }
  int lo = 0, hi = NN;
  while (lo < hi) {
    int mid = (lo + hi) >> 1;
    if (batch[mid] < g) lo = mid + 1; else hi = mid;
  }
  gs[g] = lo;
}

// ---------- fused projection v4: xl = x@W1l, xr = x@W1r + b1 ----------
// 512 thr = 8 waves; each wave: 8 nodes/tile, 2 tiles. x rows live in
// VGPRs (coalesced float4 loads), distributed in-wave via v_readlane
// (uniform lane idx -> SGPR operand in FMA). LDS holds only the weights
// ([c][j][r], identity-staged conflict-free); 2 ds_read_b128 per c-iter.
__global__ __launch_bounds__(512) void fused_proj_kernel(
    const float* __restrict__ x, const float* __restrict__ W1l,
    const float* __restrict__ W1r, const float* __restrict__ b1,
    float* __restrict__ xl, float* __restrict__ xr) {
  __shared__ float sWl[DIN * DH];     // 32 KB, [c][j][r]
  __shared__ float sWr[DIN * DH];     // 32 KB
  for (int t0 = threadIdx.x; t0 < DIN * DH; t0 += 512) {
    int c = t0 >> 8, r = t0 & 3, jj = (t0 >> 2) & 63;
    int sidx = ((c << 2) | r) * 64 + jj;      // source [k][j]
    sWl[t0] = W1l[sidx];                      // dpos = t0: conflict-free
    sWr[t0] = W1r[sidx];
  }
  int wave = threadIdx.x >> 6;
  int j    = threadIdx.x & 63;
  float b1j = b1[j];
  __syncthreads();
  const float4* x4 = (const float4*)x;

  for (int tile = 0; tile < 2; ++tile) {
    int node0 = blockIdx.x * 128 + tile * 64 + wave * 8;
    // 8 rows = 256 float4: lane j holds flat {j, j+64, j+128, j+192}
    float4 xreg[4];
#pragma unroll
    for (int e = 0; e < 4; ++e) {
      int idx = node0 * 32 + e * 64 + j;
      if (idx > NN * 32 - 1) idx = NN * 32 - 1;
      xreg[e] = x4[idx];
    }
    float accl[8], accr[8];
#pragma unroll
    for (int s = 0; s < 8; ++s) { accl[s] = 0.f; accr[s] = 0.f; }
#pragma unroll 4
    for (int c = 0; c < 32; ++c) {
      float4 wl4 = *(const float4*)(sWl + (c << 8) + (j << 2));
      float4 wr4 = *(const float4*)(sWr + (c << 8) + (j << 2));
#pragma unroll
      for (int s = 0; s < 8; ++s) {
        int sl = ((s & 1) << 5) + c;          // uniform lane index
        float4 xv = xreg[s >> 1];
        float x0 = __int_as_float(__builtin_amdgcn_readlane(__float_as_int(xv.x), sl));
        float x1 = __int_as_float(__builtin_amdgcn_readlane(__float_as_int(xv.y), sl));
        float x2 = __int_as_float(__builtin_amdgcn_readlane(__float_as_int(xv.z), sl));
        float x3 = __int_as_float(__builtin_amdgcn_readlane(__float_as_int(xv.w), sl));
        accl[s] = fmaf(x0, wl4.x, accl[s]);
        accr[s] = fmaf(x0, wr4.x, accr[s]);
        accl[s] = fmaf(x1, wl4.y, accl[s]);
        accr[s] = fmaf(x1, wr4.y, accr[s]);
        accl[s] = fmaf(x2, wl4.z, accl[s]);
        accr[s] = fmaf(x2, wr4.z, accr[s]);
        accl[s] = fmaf(x3, wl4.w, accl[s]);
        accr[s] = fmaf(x3, wr4.w, accr[s]);
      }
    }
#pragma unroll
    for (int s = 0; s < 8; ++s) {
      int node = node0 + s;
      if (node < NN) {
        xl[(size_t)node * DH + j] = accl[s];
        xr[(size_t)node * DH + j] = accr[s] + b1j;
      }
    }
  }
}

// ---------- mean aggregation via gather: 16 lanes x float4 per node ----------
template <bool RELU_ADD>
__global__ __launch_bounds__(256) void gather_kernel(
    const float4* __restrict__ feat4, const int* __restrict__ row_start,
    const int* __restrict__ eidx, const float4* __restrict__ add4,
    float4* __restrict__ out4) {
  int t = blockIdx.x * 256 + threadIdx.x;
  int node = t >> 4;
  if (node >= NN) return;
  int fl = t & 15;
  int rs = row_start[node], re = row_start[node + 1];
  float ax = 0.f, ay = 0.f, az = 0.f, aw = 0.f;
  int k = rs;
  for (; k + 8 <= re; k += 8) {           // 8 float4 loads in flight
    float4 v[8];
#pragma unroll
    for (int u = 0; u < 8; ++u) v[u] = feat4[(size_t)eidx[k + u] * 16 + fl];
#pragma unroll
    for (int u = 0; u < 8; ++u) {
      ax += v[u].x; ay += v[u].y; az += v[u].z; aw += v[u].w;
    }
  }
  for (; k + 2 <= re; k += 2) {
    float4 v0 = feat4[(size_t)eidx[k] * 16 + fl];
    float4 v1 = feat4[(size_t)eidx[k + 1] * 16 + fl];
    ax += v0.x + v1.x; ay += v0.y + v1.y;
    az += v0.z + v1.z; aw += v0.w + v1.w;
  }
  if (k < re) {
    float4 v = feat4[(size_t)eidx[k] * 16 + fl];
    ax += v.x; ay += v.y; az += v.z; aw += v.w;
  }
  float inv = 1.0f / fmaxf((float)(re - rs), 1.0f);
  ax *= inv; ay *= inv; az *= inv; aw *= inv;
  if (RELU_ADD) {
    float4 a = add4[(size_t)node * 16 + fl];
    ax = fmaxf(ax + a.x, 0.f); ay = fmaxf(ay + a.y, 0.f);
    az = fmaxf(az + a.z, 0.f); aw = fmaxf(aw + a.w, 0.f);
  }
  out4[(size_t)node * 16 + fl] = make_float4(ax, ay, az, aw);
}

// ---------- per-graph segment-sum of h and mean2 ----------
__global__ __launch_bounds__(256) void pool_kernel(
    const float* __restrict__ h, const float* __restrict__ m,
    const int* __restrict__ gs, float* __restrict__ hs,
    float* __restrict__ ms) {
  int g = blockIdx.x;
  int start = gs[g], end = gs[g + 1];
  int slot = threadIdx.x >> 6, j = threadIdx.x & 63;
  float sh = 0.f, sm = 0.f;
  for (int n = start + slot; n < end; n += 4) {
    sh += h[(size_t)n * DH + j];
    sm += m[(size_t)n * DH + j];
  }
  __shared__ float red[2][4][DH];
  red[0][slot][j] = sh;
  red[1][slot][j] = sm;
  __syncthreads();
  if (slot == 0) {
    sh = red[0][0][j] + red[0][1][j] + red[0][2][j] + red[0][3][j];
    sm = red[1][0][j] + red[1][1][j] + red[1][2][j] + red[1][3][j];
    hs[g * DH + j] = sh;
    ms[g * DH + j] = sm;
  }
}

// ---------- final tiny matmul ----------
__global__ __launch_bounds__(128) void final_kernel(
    const float* __restrict__ hs, const float* __restrict__ ms,
    const float* __restrict__ W2l, const float* __restrict__ W2r,
    const float* __restrict__ b2, const int* __restrict__ gs,
    float* __restrict__ out) {
  int g = blockIdx.x;
  int j = threadIdx.x;
  float n = (float)(gs[g + 1] - gs[g]);
  float acc = 0.f;
#pragma unroll 8
  for (int k = 0; k < DH; ++k)
    acc += ms[g * DH + k] * W2l[k * DOUT + j] + hs[g * DH + k] * W2r[k * DOUT + j];
  float inv = 1.0f / fmaxf(n, 1.0f);
  out[g * DOUT + j] = (acc + n * b2[j]) * inv;
}

extern "C" void kernel_launch(void* const* d_in, const int* in_sizes, int n_in,
                              void* d_out, int out_size, void* d_ws, size_t ws_size,
                              hipStream_t stream) {
  (void)in_sizes; (void)n_in; (void)out_size; (void)ws_size;
  const float* x   = (const float*)d_in[0];
  const float* W1l = (const float*)d_in[1];
  const float* W1r = (const float*)d_in[2];
  const float* b1  = (const float*)d_in[3];
  const float* W2l = (const float*)d_in[4];
  const float* W2r = (const float*)d_in[5];
  const float* b2  = (const float*)d_in[6];
  const int*   ei  = (const int*)d_in[7];
  const int*   batch = (const int*)d_in[8];
  const int* src = ei;            // edge_index[0, :]
  const int* dst = ei + NE;       // edge_index[1, :]
  float* out = (float*)d_out;

  char* ws = (char*)d_ws;
  float* bufA     = (float*)(ws);                    // 25,600,000 B (xl, then mean2)
  float* bufB     = (float*)(ws + 25600000);         // 25,600,000 B (h)
  float* bufC     = (float*)(ws + 51200000);         // 25,600,000 B (xr)
  // part/cnt/scanned overlay bufC: all dead before fused_proj writes xr
  int*  part      = (int*)(ws + 51200000);           //  6,400,000 B
  int*  cnt       = (int*)(ws + 57600000);           //    400,384 B (MSZ)
  int*  scanned   = (int*)(ws + 58000384);           //    400,384 B (MSZ)
  int*  eidx      = (int*)(ws + 76800000);           //  6,400,000 B
  int*  row_start = (int*)(ws + 83200000);           //    400,004 B
  int*   gs       = (int*)(ws + 83600128);           //      2,052 B
  float* hs       = (float*)(ws + 83604224);         //    131,072 B
  float* msum     = (float*)(ws + 83735296);         //    131,072 B
  int*  partials  = (int*)(ws + 84400128);           //      1,564 B

  const int gBlocks = (NN * 16) / 256;               // 6250
  const int pBlocks = (NN + 127) / 128;              // 782

  // bucket-radix CSR build
  histA_kernel<<<256, 256, 0, stream>>>(dst, cnt);
  reduce_kernel<<<NB, 256, 0, stream>>>(cnt, partials);
  scanpart_kernel<<<1, 256, 0, stream>>>(partials);
  scanfinal_kernel<<<NB, 256, 0, stream>>>(cnt, partials, scanned);
  partA_kernel<<<256, 256, 0, stream>>>(src, dst, scanned, part);
  bucket_csr_kernel<<<NB, 256, 0, stream>>>(part, scanned, row_start, eidx);
  bounds_kernel<<<3, 256, 0, stream>>>(batch, gs);

  // layer 1
  fused_proj_kernel<<<pBlocks, 512, 0, stream>>>(x, W1l, W1r, b1, bufA, bufC);
  gather_kernel<true><<<gBlocks, 256, 0, stream>>>(
      (const float4*)bufA, row_start, eidx, (const float4*)bufC, (float4*)bufB);

  // layer 2 aggregation
  gather_kernel<false><<<gBlocks, 256, 0, stream>>>(
      (const float4*)bufB, row_start, eidx, nullptr, (float4*)bufA);

  // pool-then-matmul
  pool_kernel<<<NG, 256, 0, stream>>>(bufB, bufA, gs, hs, msum);
  final_kernel<<<NG, 128, 0, stream>>>(hs, msum, W2l, W2r, b2, gs, out);
}

// Round 10
// 337.020 us; speedup vs baseline: 1.1486x; 1.1486x over previous
//
#include <hip/hip_runtime.h>

#define NN   100000
#define NE   1600000
#define DIN  128
#define DH   64
#define DOUT 128
#define NG   512

#define NB   391     // dst buckets of 256 nodes: ceil(NN/256)
#define EPB  6250    // edges per partition block: NE/256
#define MSZ  (NB*256) // 100,096 — scan length

typedef short short8 __attribute__((ext_vector_type(8)));
typedef float floatx4 __attribute__((ext_vector_type(4)));

// ---------- radix pass A1: per-(block,bucket) histogram ----------
__global__ __launch_bounds__(256) void histA_kernel(
    const int* __restrict__ dst, int* __restrict__ cnt) {
  __shared__ int h[NB];
  for (int i = threadIdx.x; i < NB; i += 256) h[i] = 0;
  __syncthreads();
  int start = blockIdx.x * EPB, end = start + EPB;
  for (int e = start + threadIdx.x; e < end; e += 256)
    atomicAdd(&h[dst[e] >> 8], 1);
  __syncthreads();
  for (int b = threadIdx.x; b < NB; b += 256)
    cnt[b * 256 + blockIdx.x] = h[b];   // bucket-major layout
}

// ---------- scan pass 1: per-block sums ----------
__global__ __launch_bounds__(256) void reduce_kernel(
    const int* __restrict__ cnt, int* __restrict__ partials) {
  __shared__ int s[256];
  int i = blockIdx.x * 256 + threadIdx.x;
  s[threadIdx.x] = cnt[i];
  __syncthreads();
  for (int off = 128; off > 0; off >>= 1) {
    if (threadIdx.x < off) s[threadIdx.x] += s[threadIdx.x + off];
    __syncthreads();
  }
  if (threadIdx.x == 0) partials[blockIdx.x] = s[0];
}

// ---------- scan pass 2: exclusive scan of NB partials (1 block) ----------
__global__ __launch_bounds__(256) void scanpart_kernel(int* __restrict__ partials) {
  __shared__ int s[NB];
  for (int i = threadIdx.x; i < NB; i += 256) s[i] = partials[i];
  __syncthreads();
  if (threadIdx.x == 0) {
    int run = 0;
    for (int i = 0; i < NB; ++i) { int v = s[i]; s[i] = run; run += v; }
  }
  __syncthreads();
  for (int i = threadIdx.x; i < NB; i += 256) partials[i] = s[i];
}

// ---------- scan pass 3: per-block exclusive scan + offset ----------
__global__ __launch_bounds__(256) void scanfinal_kernel(
    const int* __restrict__ cnt, const int* __restrict__ partials,
    int* __restrict__ scanned) {
  __shared__ int s[256];
  int t = threadIdx.x;
  int i = blockIdx.x * 256 + t;
  int c = cnt[i];
  s[t] = c;
  __syncthreads();
  for (int off = 1; off < 256; off <<= 1) {
    int v = (t >= off) ? s[t - off] : 0;
    __syncthreads();
    s[t] += v;
    __syncthreads();
  }
  scanned[i] = s[t] - c + partials[blockIdx.x];
}

// ---------- radix pass A2: partition packed edges into buckets ----------
__global__ __launch_bounds__(256) void partA_kernel(
    const int* __restrict__ src, const int* __restrict__ dst,
    const int* __restrict__ scanned, int* __restrict__ part) {
  __shared__ int cur[NB];
  for (int i = threadIdx.x; i < NB; i += 256)
    cur[i] = scanned[i * 256 + blockIdx.x];
  __syncthreads();
  int start = blockIdx.x * EPB, end = start + EPB;
  for (int e = start + threadIdx.x; e < end; e += 256) {
    int d = dst[e], s = src[e];
    int pos = atomicAdd(&cur[d >> 8], 1);
    part[pos] = ((d & 255) << 17) | s;
  }
}

// ---------- radix pass B: per-bucket CSR (row_start + eidx) ----------
__global__ __launch_bounds__(256) void bucket_csr_kernel(
    const int* __restrict__ part, const int* __restrict__ scanned,
    int* __restrict__ row_start, int* __restrict__ eidx) {
  int b = blockIdx.x, t = threadIdx.x;
  int ebeg = scanned[b * 256];
  int eend = (b == NB - 1) ? NE : scanned[(b + 1) * 256];
  int nbase = b << 8;
  int nloc = NN - nbase; if (nloc > 256) nloc = 256;
  __shared__ int cntL[256];
  __shared__ int exclL[256];
  cntL[t] = 0;
  __syncthreads();
  for (int e = ebeg + t; e < eend; e += 256)
    atomicAdd(&cntL[part[e] >> 17], 1);
  __syncthreads();
  int c = cntL[t];
  exclL[t] = c;
  __syncthreads();
  for (int off = 1; off < 256; off <<= 1) {
    int v = (t >= off) ? exclL[t - off] : 0;
    __syncthreads();
    exclL[t] += v;
    __syncthreads();
  }
  int excl = exclL[t] - c;
  if (t < nloc) row_start[nbase + t] = ebeg + excl;
  if (b == NB - 1 && t == 0) row_start[NN] = NE;
  cntL[t] = excl;                 // reuse as cursor
  __syncthreads();
  for (int e = ebeg + t; e < eend; e += 256) {
    int v = part[e];
    int pos = atomicAdd(&cntL[v >> 17], 1);
    eidx[ebeg + pos] = v & 0x1FFFF;
  }
}

// ---------- graph boundaries: batch is sorted -> binary search ----------
__global__ __launch_bounds__(256) void bounds_kernel(
    const int* __restrict__ batch, int* __restrict__ gs) {
  int g = blockIdx.x * 256 + threadIdx.x;
  if (g > NG) return;
  if (g == NG) { gs[NG] = NN; return; }
  int lo = 0, hi = NN;
  while (lo < hi) {
    int mid = (lo + hi) >> 1;
    if (batch[mid] < g) lo = mid + 1; else hi = mid;
  }
  gs[g] = lo;
}

// ---------- fused projection v5 (MFMA): xl = x@W1l, xr = x@W1r + b1 ----------
// bf16 hi/lo split: x@W ~= xh@Wh + xh@Wlo + xlo@Wh (fp32 accum), err ~2^-16.
// mfma_f32_16x16x32_bf16, HW-verified layouts:
//   A[m=lane&15][k=(lane>>4)*8+j], B[k=(lane>>4)*8+j][n=lane&15],
//   C col=lane&15, row=(lane>>4)*4+reg.
// Weights pre-split into 64KB of lane-ordered LDS fragments (one-time);
// x converted in-register from coalesced float4 loads (each row read once).
__global__ __launch_bounds__(256) void proj_mfma_kernel(
    const float* __restrict__ x, const float* __restrict__ W1l,
    const float* __restrict__ W1r, const float* __restrict__ b1,
    float* __restrict__ xl, float* __restrict__ xr) {
  __shared__ short sB[32768];   // 64 KB: [kt][mat][jt][hilo][lane][8]
  for (int i = threadIdx.x; i < DIN * DH; i += 256) {
    int k = i >> 6, n = i & 63;
    int kt = k >> 5, kin = k & 31;
    int lane = ((kin >> 3) << 4) | (n & 15);
    int j8 = kin & 7;
    int jt = n >> 4;
    float wl = W1l[i], wr = W1r[i];
    unsigned bl_ = __float_as_uint(wl);
    unsigned br_ = __float_as_uint(wr);
    short hl = (short)(bl_ >> 16);
    short hr = (short)(br_ >> 16);
    float rl = wl - __uint_as_float(bl_ & 0xFFFF0000u);
    float rr = wr - __uint_as_float(br_ & 0xFFFF0000u);
    short ll = (short)(__float_as_uint(rl) >> 16);
    short lr = (short)(__float_as_uint(rr) >> 16);
    // unit = ((kt*2 + mat)*4 + jt)*2 + hilo
    int base0 = (((kt * 2 + 0) * 4 + jt) * 2) * 512 + lane * 8 + j8;
    int base1 = (((kt * 2 + 1) * 4 + jt) * 2) * 512 + lane * 8 + j8;
    sB[base0]       = hl;   // mat0 hi
    sB[base0 + 512] = ll;   // mat0 lo
    sB[base1]       = hr;   // mat1 hi
    sB[base1 + 512] = lr;   // mat1 lo
  }
  __syncthreads();

  int wave = threadIdx.x >> 6;
  int lane = threadIdx.x & 63;
  int m = lane & 15, q = lane >> 4;
  int tile = blockIdx.x * 4 + wave;
  if (tile >= 6250) return;      // no further barriers
  int node0 = tile * 16;

  const float4* xr4 = (const float4*)x + (size_t)(node0 + m) * 32 + q * 2;
  floatx4 acc[8];                // [mat*4 + jt]
#pragma unroll
  for (int a = 0; a < 8; ++a) acc[a] = (floatx4){0.f, 0.f, 0.f, 0.f};

#pragma unroll
  for (int kt = 0; kt < 4; ++kt) {
    float4 a0 = xr4[kt * 8];
    float4 a1 = xr4[kt * 8 + 1];
    float af[8] = {a0.x, a0.y, a0.z, a0.w, a1.x, a1.y, a1.z, a1.w};
    short8 ah, al;
#pragma unroll
    for (int e = 0; e < 8; ++e) {
      unsigned b = __float_as_uint(af[e]);
      ah[e] = (short)(b >> 16);
      float lo = af[e] - __uint_as_float(b & 0xFFFF0000u);
      al[e] = (short)(__float_as_uint(lo) >> 16);
    }
#pragma unroll
    for (int mat = 0; mat < 2; ++mat) {
#pragma unroll
      for (int jt = 0; jt < 4; ++jt) {
        int unit = ((kt * 2 + mat) * 4 + jt) * 2;
        short8 bh = *(const short8*)(sB + unit * 512 + lane * 8);
        short8 bl = *(const short8*)(sB + (unit + 1) * 512 + lane * 8);
        floatx4 c = acc[mat * 4 + jt];
        c = __builtin_amdgcn_mfma_f32_16x16x32_bf16(ah, bh, c, 0, 0, 0);
        c = __builtin_amdgcn_mfma_f32_16x16x32_bf16(ah, bl, c, 0, 0, 0);
        c = __builtin_amdgcn_mfma_f32_16x16x32_bf16(al, bh, c, 0, 0, 0);
        acc[mat * 4 + jt] = c;
      }
    }
  }

#pragma unroll
  for (int jt = 0; jt < 4; ++jt) {
    int j = jt * 16 + m;
    float bj = b1[j];
    floatx4 cl = acc[jt];
    floatx4 cr = acc[4 + jt];
#pragma unroll
    for (int r = 0; r < 4; ++r) {
      int node = node0 + q * 4 + r;
      xl[(size_t)node * DH + j] = cl[r];
      xr[(size_t)node * DH + j] = cr[r] + bj;
    }
  }
}

// ---------- mean aggregation via gather: 16 lanes x float4 per node ----------
template <bool RELU_ADD>
__global__ __launch_bounds__(256) void gather_kernel(
    const float4* __restrict__ feat4, const int* __restrict__ row_start,
    const int* __restrict__ eidx, const float4* __restrict__ add4,
    float4* __restrict__ out4) {
  int t = blockIdx.x * 256 + threadIdx.x;
  int node = t >> 4;
  if (node >= NN) return;
  int fl = t & 15;
  int rs = row_start[node], re = row_start[node + 1];
  float ax = 0.f, ay = 0.f, az = 0.f, aw = 0.f;
  int k = rs;
  for (; k + 8 <= re; k += 8) {           // 8 float4 loads in flight
    float4 v[8];
#pragma unroll
    for (int u = 0; u < 8; ++u) v[u] = feat4[(size_t)eidx[k + u] * 16 + fl];
#pragma unroll
    for (int u = 0; u < 8; ++u) {
      ax += v[u].x; ay += v[u].y; az += v[u].z; aw += v[u].w;
    }
  }
  for (; k + 2 <= re; k += 2) {
    float4 v0 = feat4[(size_t)eidx[k] * 16 + fl];
    float4 v1 = feat4[(size_t)eidx[k + 1] * 16 + fl];
    ax += v0.x + v1.x; ay += v0.y + v1.y;
    az += v0.z + v1.z; aw += v0.w + v1.w;
  }
  if (k < re) {
    float4 v = feat4[(size_t)eidx[k] * 16 + fl];
    ax += v.x; ay += v.y; az += v.z; aw += v.w;
  }
  float inv = 1.0f / fmaxf((float)(re - rs), 1.0f);
  ax *= inv; ay *= inv; az *= inv; aw *= inv;
  if (RELU_ADD) {
    float4 a = add4[(size_t)node * 16 + fl];
    ax = fmaxf(ax + a.x, 0.f); ay = fmaxf(ay + a.y, 0.f);
    az = fmaxf(az + a.z, 0.f); aw = fmaxf(aw + a.w, 0.f);
  }
  out4[(size_t)node * 16 + fl] = make_float4(ax, ay, az, aw);
}

// ---------- per-graph segment-sum of h and mean2 ----------
__global__ __launch_bounds__(256) void pool_kernel(
    const float* __restrict__ h, const float* __restrict__ m,
    const int* __restrict__ gs, float* __restrict__ hs,
    float* __restrict__ ms) {
  int g = blockIdx.x;
  int start = gs[g], end = gs[g + 1];
  int slot = threadIdx.x >> 6, j = threadIdx.x & 63;
  float sh = 0.f, sm = 0.f;
  for (int n = start + slot; n < end; n += 4) {
    sh += h[(size_t)n * DH + j];
    sm += m[(size_t)n * DH + j];
  }
  __shared__ float red[2][4][DH];
  red[0][slot][j] = sh;
  red[1][slot][j] = sm;
  __syncthreads();
  if (slot == 0) {
    sh = red[0][0][j] + red[0][1][j] + red[0][2][j] + red[0][3][j];
    sm = red[1][0][j] + red[1][1][j] + red[1][2][j] + red[1][3][j];
    hs[g * DH + j] = sh;
    ms[g * DH + j] = sm;
  }
}

// ---------- final tiny matmul ----------
__global__ __launch_bounds__(128) void final_kernel(
    const float* __restrict__ hs, const float* __restrict__ ms,
    const float* __restrict__ W2l, const float* __restrict__ W2r,
    const float* __restrict__ b2, const int* __restrict__ gs,
    float* __restrict__ out) {
  int g = blockIdx.x;
  int j = threadIdx.x;
  float n = (float)(gs[g + 1] - gs[g]);
  float acc = 0.f;
#pragma unroll 8
  for (int k = 0; k < DH; ++k)
    acc += ms[g * DH + k] * W2l[k * DOUT + j] + hs[g * DH + k] * W2r[k * DOUT + j];
  float inv = 1.0f / fmaxf(n, 1.0f);
  out[g * DOUT + j] = (acc + n * b2[j]) * inv;
}

extern "C" void kernel_launch(void* const* d_in, const int* in_sizes, int n_in,
                              void* d_out, int out_size, void* d_ws, size_t ws_size,
                              hipStream_t stream) {
  (void)in_sizes; (void)n_in; (void)out_size; (void)ws_size;
  const float* x   = (const float*)d_in[0];
  const float* W1l = (const float*)d_in[1];
  const float* W1r = (const float*)d_in[2];
  const float* b1  = (const float*)d_in[3];
  const float* W2l = (const float*)d_in[4];
  const float* W2r = (const float*)d_in[5];
  const float* b2  = (const float*)d_in[6];
  const int*   ei  = (const int*)d_in[7];
  const int*   batch = (const int*)d_in[8];
  const int* src = ei;            // edge_index[0, :]
  const int* dst = ei + NE;       // edge_index[1, :]
  float* out = (float*)d_out;

  char* ws = (char*)d_ws;
  float* bufA     = (float*)(ws);                    // 25,600,000 B (xl, then mean2)
  float* bufB     = (float*)(ws + 25600000);         // 25,600,000 B (h)
  float* bufC     = (float*)(ws + 51200000);         // 25,600,000 B (xr)
  // part/cnt/scanned overlay bufC: all dead before proj writes xr
  int*  part      = (int*)(ws + 51200000);           //  6,400,000 B
  int*  cnt       = (int*)(ws + 57600000);           //    400,384 B (MSZ)
  int*  scanned   = (int*)(ws + 58000384);           //    400,384 B (MSZ)
  int*  eidx      = (int*)(ws + 76800000);           //  6,400,000 B
  int*  row_start = (int*)(ws + 83200000);           //    400,004 B
  int*   gs       = (int*)(ws + 83600128);           //      2,052 B
  float* hs       = (float*)(ws + 83604224);         //    131,072 B
  float* msum     = (float*)(ws + 83735296);         //    131,072 B
  int*  partials  = (int*)(ws + 84400128);           //      1,564 B

  const int gBlocks = (NN * 16) / 256;               // 6250
  const int pBlocks = 1563;                          // ceil(6250 tiles / 4 waves)

  // bucket-radix CSR build
  histA_kernel<<<256, 256, 0, stream>>>(dst, cnt);
  reduce_kernel<<<NB, 256, 0, stream>>>(cnt, partials);
  scanpart_kernel<<<1, 256, 0, stream>>>(partials);
  scanfinal_kernel<<<NB, 256, 0, stream>>>(cnt, partials, scanned);
  partA_kernel<<<256, 256, 0, stream>>>(src, dst, scanned, part);
  bucket_csr_kernel<<<NB, 256, 0, stream>>>(part, scanned, row_start, eidx);
  bounds_kernel<<<3, 256, 0, stream>>>(batch, gs);

  // layer 1
  proj_mfma_kernel<<<pBlocks, 256, 0, stream>>>(x, W1l, W1r, b1, bufA, bufC);
  gather_kernel<true><<<gBlocks, 256, 0, stream>>>(
      (const float4*)bufA, row_start, eidx, (const float4*)bufC, (float4*)bufB);

  // layer 2 aggregation
  gather_kernel<false><<<gBlocks, 256, 0, stream>>>(
      (const float4*)bufB, row_start, eidx, nullptr, (float4*)bufA);

  // pool-then-matmul
  pool_kernel<<<NG, 256, 0, stream>>>(bufB, bufA, gs, hs, msum);
  final_kernel<<<NG, 128, 0, stream>>>(hs, msum, W2l, W2r, b2, gs, out);
}

// Round 11
// 325.723 us; speedup vs baseline: 1.1884x; 1.0347x over previous
//
#include <hip/hip_runtime.h>

#define NN   100000
#define NE   1600000
#define DIN  128
#define DH   64
#define DOUT 128
#define NG   512

#define NB   391     // dst buckets of 256 nodes: ceil(NN/256)
#define EPB  6250    // edges per partition block: NE/256
#define MSZ  (NB*256) // 100,096 — scan length

typedef short short8 __attribute__((ext_vector_type(8)));
typedef float floatx4 __attribute__((ext_vector_type(4)));

// ---------- radix pass A1: per-(block,bucket) histogram ----------
__global__ __launch_bounds__(256) void histA_kernel(
    const int* __restrict__ dst, int* __restrict__ cnt) {
  __shared__ int h[NB];
  for (int i = threadIdx.x; i < NB; i += 256) h[i] = 0;
  __syncthreads();
  int start = blockIdx.x * EPB, end = start + EPB;
  for (int e = start + threadIdx.x; e < end; e += 256)
    atomicAdd(&h[dst[e] >> 8], 1);
  __syncthreads();
  for (int b = threadIdx.x; b < NB; b += 256)
    cnt[b * 256 + blockIdx.x] = h[b];   // bucket-major layout
}

// ---------- scan pass 1: per-block sums ----------
__global__ __launch_bounds__(256) void reduce_kernel(
    const int* __restrict__ cnt, int* __restrict__ partials) {
  __shared__ int s[256];
  int i = blockIdx.x * 256 + threadIdx.x;
  s[threadIdx.x] = cnt[i];
  __syncthreads();
  for (int off = 128; off > 0; off >>= 1) {
    if (threadIdx.x < off) s[threadIdx.x] += s[threadIdx.x + off];
    __syncthreads();
  }
  if (threadIdx.x == 0) partials[blockIdx.x] = s[0];
}

// ---------- scan pass 2: exclusive scan of NB partials (1 block) ----------
__global__ __launch_bounds__(256) void scanpart_kernel(int* __restrict__ partials) {
  __shared__ int s[NB];
  for (int i = threadIdx.x; i < NB; i += 256) s[i] = partials[i];
  __syncthreads();
  if (threadIdx.x == 0) {
    int run = 0;
    for (int i = 0; i < NB; ++i) { int v = s[i]; s[i] = run; run += v; }
  }
  __syncthreads();
  for (int i = threadIdx.x; i < NB; i += 256) partials[i] = s[i];
}

// ---------- scan pass 3: per-block exclusive scan + offset ----------
__global__ __launch_bounds__(256) void scanfinal_kernel(
    const int* __restrict__ cnt, const int* __restrict__ partials,
    int* __restrict__ scanned) {
  __shared__ int s[256];
  int t = threadIdx.x;
  int i = blockIdx.x * 256 + t;
  int c = cnt[i];
  s[t] = c;
  __syncthreads();
  for (int off = 1; off < 256; off <<= 1) {
    int v = (t >= off) ? s[t - off] : 0;
    __syncthreads();
    s[t] += v;
    __syncthreads();
  }
  scanned[i] = s[t] - c + partials[blockIdx.x];
}

// ---------- radix pass A2: partition packed edges into buckets ----------
__global__ __launch_bounds__(256) void partA_kernel(
    const int* __restrict__ src, const int* __restrict__ dst,
    const int* __restrict__ scanned, int* __restrict__ part) {
  __shared__ int cur[NB];
  for (int i = threadIdx.x; i < NB; i += 256)
    cur[i] = scanned[i * 256 + blockIdx.x];
  __syncthreads();
  int start = blockIdx.x * EPB, end = start + EPB;
  for (int e = start + threadIdx.x; e < end; e += 256) {
    int d = dst[e], s = src[e];
    int pos = atomicAdd(&cur[d >> 8], 1);
    part[pos] = ((d & 255) << 17) | s;
  }
}

// ---------- radix pass B: per-bucket CSR (row_start + eidx) ----------
__global__ __launch_bounds__(256) void bucket_csr_kernel(
    const int* __restrict__ part, const int* __restrict__ scanned,
    int* __restrict__ row_start, int* __restrict__ eidx) {
  int b = blockIdx.x, t = threadIdx.x;
  int ebeg = scanned[b * 256];
  int eend = (b == NB - 1) ? NE : scanned[(b + 1) * 256];
  int nbase = b << 8;
  int nloc = NN - nbase; if (nloc > 256) nloc = 256;
  __shared__ int cntL[256];
  __shared__ int exclL[256];
  cntL[t] = 0;
  __syncthreads();
  for (int e = ebeg + t; e < eend; e += 256)
    atomicAdd(&cntL[part[e] >> 17], 1);
  __syncthreads();
  int c = cntL[t];
  exclL[t] = c;
  __syncthreads();
  for (int off = 1; off < 256; off <<= 1) {
    int v = (t >= off) ? exclL[t - off] : 0;
    __syncthreads();
    exclL[t] += v;
    __syncthreads();
  }
  int excl = exclL[t] - c;
  if (t < nloc) row_start[nbase + t] = ebeg + excl;
  if (b == NB - 1 && t == 0) row_start[NN] = NE;
  cntL[t] = excl;                 // reuse as cursor
  __syncthreads();
  for (int e = ebeg + t; e < eend; e += 256) {
    int v = part[e];
    int pos = atomicAdd(&cntL[v >> 17], 1);
    eidx[ebeg + pos] = v & 0x1FFFF;
  }
}

// ---------- graph boundaries: batch is sorted -> binary search ----------
__global__ __launch_bounds__(256) void bounds_kernel(
    const int* __restrict__ batch, int* __restrict__ gs) {
  int g = blockIdx.x * 256 + threadIdx.x;
  if (g > NG) return;
  if (g == NG) { gs[NG] = NN; return; }
  int lo = 0, hi = NN;
  while (lo < hi) {
    int mid = (lo + hi) >> 1;
    if (batch[mid] < g) lo = mid + 1; else hi = mid;
  }
  gs[g] = lo;
}

// ---------- one-time bf16 hi/lo weight split into fragment image ----------
// Layout (shorts): unit = ((kt*2+mat)*4+jt)*2 + hilo; offset unit*512+lane*8+j8
__global__ __launch_bounds__(256) void split_w_kernel(
    const float* __restrict__ W1l, const float* __restrict__ W1r,
    short* __restrict__ wfrag) {
  int i = blockIdx.x * 256 + threadIdx.x;
  if (i >= DIN * DH) return;
  int k = i >> 6, n = i & 63;
  int kt = k >> 5, kin = k & 31;
  int lane = ((kin >> 3) << 4) | (n & 15);
  int j8 = kin & 7;
  int jt = n >> 4;
  float wl = W1l[i], wr = W1r[i];
  unsigned bl_ = __float_as_uint(wl);
  unsigned br_ = __float_as_uint(wr);
  short hl = (short)(bl_ >> 16);
  short hr = (short)(br_ >> 16);
  float rl = wl - __uint_as_float(bl_ & 0xFFFF0000u);
  float rr = wr - __uint_as_float(br_ & 0xFFFF0000u);
  short ll = (short)(__float_as_uint(rl) >> 16);
  short lr = (short)(__float_as_uint(rr) >> 16);
  int base0 = (((kt * 2 + 0) * 4 + jt) * 2) * 512 + lane * 8 + j8;
  int base1 = (((kt * 2 + 1) * 4 + jt) * 2) * 512 + lane * 8 + j8;
  wfrag[base0]       = hl;
  wfrag[base0 + 512] = ll;
  wfrag[base1]       = hr;
  wfrag[base1 + 512] = lr;
}

// ---------- fused projection v6 (MFMA): xl = x@W1l, xr = x@W1r + b1 ----------
// Weights pre-split in global (split_w_kernel); identity float4 staging
// (conflict-free). 2 tiles per wave with B-fragment reuse: per (kt,mat,jt)
// one bh/bl read pair feeds 6 MFMAs.
__global__ __launch_bounds__(256) void proj_mfma_kernel(
    const float* __restrict__ x, const short* __restrict__ wfrag,
    const float* __restrict__ b1, float* __restrict__ xl,
    float* __restrict__ xr) {
  __shared__ short sB[32768];   // 64 KB
  {
    const float4* wf4 = (const float4*)wfrag;
    float4* sB4 = (float4*)sB;
    for (int i = threadIdx.x; i < 4096; i += 256) sB4[i] = wf4[i];
  }
  __syncthreads();

  int wave = threadIdx.x >> 6;
  int lane = threadIdx.x & 63;
  int m = lane & 15, q = lane >> 4;
  int tpair = blockIdx.x * 4 + wave;
  int tile0 = tpair * 2, tile1 = tile0 + 1;
  if (tile0 >= 6250) return;

  int r0 = tile0 * 16 + m;
  int r1 = tile1 * 16 + m; if (r1 > NN - 1) r1 = NN - 1;
  const float4* xa = (const float4*)x + (size_t)r0 * 32 + q * 2;
  const float4* xb = (const float4*)x + (size_t)r1 * 32 + q * 2;

  floatx4 acc0[8], acc1[8];
#pragma unroll
  for (int a = 0; a < 8; ++a) {
    acc0[a] = (floatx4){0.f, 0.f, 0.f, 0.f};
    acc1[a] = (floatx4){0.f, 0.f, 0.f, 0.f};
  }

#pragma unroll
  for (int kt = 0; kt < 4; ++kt) {
    float4 p0 = xa[kt * 8];
    float4 p1 = xa[kt * 8 + 1];
    float4 p2 = xb[kt * 8];
    float4 p3 = xb[kt * 8 + 1];
    float af0[8] = {p0.x, p0.y, p0.z, p0.w, p1.x, p1.y, p1.z, p1.w};
    float af1[8] = {p2.x, p2.y, p2.z, p2.w, p3.x, p3.y, p3.z, p3.w};
    short8 ah0, al0, ah1, al1;
#pragma unroll
    for (int e = 0; e < 8; ++e) {
      unsigned b0 = __float_as_uint(af0[e]);
      ah0[e] = (short)(b0 >> 16);
      float lo0 = af0[e] - __uint_as_float(b0 & 0xFFFF0000u);
      al0[e] = (short)(__float_as_uint(lo0) >> 16);
      unsigned b1_ = __float_as_uint(af1[e]);
      ah1[e] = (short)(b1_ >> 16);
      float lo1 = af1[e] - __uint_as_float(b1_ & 0xFFFF0000u);
      al1[e] = (short)(__float_as_uint(lo1) >> 16);
    }
#pragma unroll
    for (int mat = 0; mat < 2; ++mat) {
#pragma unroll
      for (int jt = 0; jt < 4; ++jt) {
        int unit = ((kt * 2 + mat) * 4 + jt) * 2;
        short8 bh = *(const short8*)(sB + unit * 512 + lane * 8);
        short8 bl = *(const short8*)(sB + (unit + 1) * 512 + lane * 8);
        floatx4 c0 = acc0[mat * 4 + jt];
        c0 = __builtin_amdgcn_mfma_f32_16x16x32_bf16(ah0, bh, c0, 0, 0, 0);
        c0 = __builtin_amdgcn_mfma_f32_16x16x32_bf16(ah0, bl, c0, 0, 0, 0);
        c0 = __builtin_amdgcn_mfma_f32_16x16x32_bf16(al0, bh, c0, 0, 0, 0);
        acc0[mat * 4 + jt] = c0;
        floatx4 c1 = acc1[mat * 4 + jt];
        c1 = __builtin_amdgcn_mfma_f32_16x16x32_bf16(ah1, bh, c1, 0, 0, 0);
        c1 = __builtin_amdgcn_mfma_f32_16x16x32_bf16(ah1, bl, c1, 0, 0, 0);
        c1 = __builtin_amdgcn_mfma_f32_16x16x32_bf16(al1, bh, c1, 0, 0, 0);
        acc1[mat * 4 + jt] = c1;
      }
    }
  }

#pragma unroll
  for (int jt = 0; jt < 4; ++jt) {
    int j = jt * 16 + m;
    float bj = b1[j];
    floatx4 cl0 = acc0[jt], cr0 = acc0[4 + jt];
    floatx4 cl1 = acc1[jt], cr1 = acc1[4 + jt];
#pragma unroll
    for (int r = 0; r < 4; ++r) {
      int n0 = tile0 * 16 + q * 4 + r;
      xl[(size_t)n0 * DH + j] = cl0[r];
      xr[(size_t)n0 * DH + j] = cr0[r] + bj;
    }
    if (tile1 < 6250) {
#pragma unroll
      for (int r = 0; r < 4; ++r) {
        int n1 = tile1 * 16 + q * 4 + r;
        xl[(size_t)n1 * DH + j] = cl1[r];
        xr[(size_t)n1 * DH + j] = cr1[r] + bj;
      }
    }
  }
}

// ---------- mean aggregation via gather: 16 lanes x float4 per node ----------
template <bool RELU_ADD>
__global__ __launch_bounds__(256) void gather_kernel(
    const float4* __restrict__ feat4, const int* __restrict__ row_start,
    const int* __restrict__ eidx, const float4* __restrict__ add4,
    float4* __restrict__ out4) {
  int t = blockIdx.x * 256 + threadIdx.x;
  int node = t >> 4;
  if (node >= NN) return;
  int fl = t & 15;
  int rs = row_start[node], re = row_start[node + 1];
  float ax = 0.f, ay = 0.f, az = 0.f, aw = 0.f;
  int k = rs;
  for (; k + 8 <= re; k += 8) {           // 8 float4 loads in flight
    float4 v[8];
#pragma unroll
    for (int u = 0; u < 8; ++u) v[u] = feat4[(size_t)eidx[k + u] * 16 + fl];
#pragma unroll
    for (int u = 0; u < 8; ++u) {
      ax += v[u].x; ay += v[u].y; az += v[u].z; aw += v[u].w;
    }
  }
  for (; k + 2 <= re; k += 2) {
    float4 v0 = feat4[(size_t)eidx[k] * 16 + fl];
    float4 v1 = feat4[(size_t)eidx[k + 1] * 16 + fl];
    ax += v0.x + v1.x; ay += v0.y + v1.y;
    az += v0.z + v1.z; aw += v0.w + v1.w;
  }
  if (k < re) {
    float4 v = feat4[(size_t)eidx[k] * 16 + fl];
    ax += v.x; ay += v.y; az += v.z; aw += v.w;
  }
  float inv = 1.0f / fmaxf((float)(re - rs), 1.0f);
  ax *= inv; ay *= inv; az *= inv; aw *= inv;
  if (RELU_ADD) {
    float4 a = add4[(size_t)node * 16 + fl];
    ax = fmaxf(ax + a.x, 0.f); ay = fmaxf(ay + a.y, 0.f);
    az = fmaxf(az + a.z, 0.f); aw = fmaxf(aw + a.w, 0.f);
  }
  out4[(size_t)node * 16 + fl] = make_float4(ax, ay, az, aw);
}

// ---------- per-graph segment-sum of h and mean2 ----------
__global__ __launch_bounds__(256) void pool_kernel(
    const float* __restrict__ h, const float* __restrict__ m,
    const int* __restrict__ gs, float* __restrict__ hs,
    float* __restrict__ ms) {
  int g = blockIdx.x;
  int start = gs[g], end = gs[g + 1];
  int slot = threadIdx.x >> 6, j = threadIdx.x & 63;
  float sh = 0.f, sm = 0.f;
  for (int n = start + slot; n < end; n += 4) {
    sh += h[(size_t)n * DH + j];
    sm += m[(size_t)n * DH + j];
  }
  __shared__ float red[2][4][DH];
  red[0][slot][j] = sh;
  red[1][slot][j] = sm;
  __syncthreads();
  if (slot == 0) {
    sh = red[0][0][j] + red[0][1][j] + red[0][2][j] + red[0][3][j];
    sm = red[1][0][j] + red[1][1][j] + red[1][2][j] + red[1][3][j];
    hs[g * DH + j] = sh;
    ms[g * DH + j] = sm;
  }
}

// ---------- final tiny matmul ----------
__global__ __launch_bounds__(128) void final_kernel(
    const float* __restrict__ hs, const float* __restrict__ ms,
    const float* __restrict__ W2l, const float* __restrict__ W2r,
    const float* __restrict__ b2, const int* __restrict__ gs,
    float* __restrict__ out) {
  int g = blockIdx.x;
  int j = threadIdx.x;
  float n = (float)(gs[g + 1] - gs[g]);
  float acc = 0.f;
#pragma unroll 8
  for (int k = 0; k < DH; ++k)
    acc += ms[g * DH + k] * W2l[k * DOUT + j] + hs[g * DH + k] * W2r[k * DOUT + j];
  float inv = 1.0f / fmaxf(n, 1.0f);
  out[g * DOUT + j] = (acc + n * b2[j]) * inv;
}

extern "C" void kernel_launch(void* const* d_in, const int* in_sizes, int n_in,
                              void* d_out, int out_size, void* d_ws, size_t ws_size,
                              hipStream_t stream) {
  (void)in_sizes; (void)n_in; (void)out_size; (void)ws_size;
  const float* x   = (const float*)d_in[0];
  const float* W1l = (const float*)d_in[1];
  const float* W1r = (const float*)d_in[2];
  const float* b1  = (const float*)d_in[3];
  const float* W2l = (const float*)d_in[4];
  const float* W2r = (const float*)d_in[5];
  const float* b2  = (const float*)d_in[6];
  const int*   ei  = (const int*)d_in[7];
  const int*   batch = (const int*)d_in[8];
  const int* src = ei;            // edge_index[0, :]
  const int* dst = ei + NE;       // edge_index[1, :]
  float* out = (float*)d_out;

  char* ws = (char*)d_ws;
  float* bufA     = (float*)(ws);                    // 25,600,000 B (xl, then mean2)
  float* bufB     = (float*)(ws + 25600000);         // 25,600,000 B (h)
  float* bufC     = (float*)(ws + 51200000);         // 25,600,000 B (xr)
  // part/cnt/scanned overlay bufC: all dead before proj writes xr
  int*  part      = (int*)(ws + 51200000);           //  6,400,000 B
  int*  cnt       = (int*)(ws + 57600000);           //    400,384 B (MSZ)
  int*  scanned   = (int*)(ws + 58000384);           //    400,384 B (MSZ)
  int*  eidx      = (int*)(ws + 76800000);           //  6,400,000 B
  int*  row_start = (int*)(ws + 83200000);           //    400,004 B
  int*   gs       = (int*)(ws + 83600128);           //      2,052 B
  float* hs       = (float*)(ws + 83604224);         //    131,072 B
  float* msum     = (float*)(ws + 83735296);         //    131,072 B (end 83,866,368)
  short* wfrag    = (short*)(ws + 83900032);         //     65,536 B (end 83,965,568)
  int*  partials  = (int*)(ws + 84400128);           //      1,564 B

  const int gBlocks = (NN * 16) / 256;               // 6250
  const int pBlocks = 782;                           // ceil(3125 pairs / 4 waves)

  // bucket-radix CSR build + weight split (independent)
  split_w_kernel<<<32, 256, 0, stream>>>(W1l, W1r, wfrag);
  histA_kernel<<<256, 256, 0, stream>>>(dst, cnt);
  reduce_kernel<<<NB, 256, 0, stream>>>(cnt, partials);
  scanpart_kernel<<<1, 256, 0, stream>>>(partials);
  scanfinal_kernel<<<NB, 256, 0, stream>>>(cnt, partials, scanned);
  partA_kernel<<<256, 256, 0, stream>>>(src, dst, scanned, part);
  bucket_csr_kernel<<<NB, 256, 0, stream>>>(part, scanned, row_start, eidx);
  bounds_kernel<<<3, 256, 0, stream>>>(batch, gs);

  // layer 1
  proj_mfma_kernel<<<pBlocks, 256, 0, stream>>>(x, wfrag, b1, bufA, bufC);
  gather_kernel<true><<<gBlocks, 256, 0, stream>>>(
      (const float4*)bufA, row_start, eidx, (const float4*)bufC, (float4*)bufB);

  // layer 2 aggregation
  gather_kernel<false><<<gBlocks, 256, 0, stream>>>(
      (const float4*)bufB, row_start, eidx, nullptr, (float4*)bufA);

  // pool-then-matmul
  pool_kernel<<<NG, 256, 0, stream>>>(bufB, bufA, gs, hs, msum);
  final_kernel<<<NG, 128, 0, stream>>>(hs, msum, W2l, W2r, b2, gs, out);
}

// Round 12
// 266.237 us; speedup vs baseline: 1.4539x; 1.2234x over previous
//
#include <hip/hip_runtime.h>

#define NN   100000
#define NE   1600000
#define DIN  128
#define DH   64
#define DOUT 128
#define NG   512

#define NB   391     // dst buckets of 256 nodes: ceil(NN/256)
#define EPB  6250    // edges per partition block: NE/256
#define MSZ  (NB*256) // 100,096 — scan length

typedef short short8 __attribute__((ext_vector_type(8)));
typedef float floatx4 __attribute__((ext_vector_type(4)));

__device__ __forceinline__ unsigned short f2bf(float f) {
  unsigned b = __float_as_uint(f);
  b += 0x7FFF + ((b >> 16) & 1);          // round-to-nearest-even
  return (unsigned short)(b >> 16);
}
__device__ __forceinline__ float bflo(unsigned u) {   // low 16 bits -> float
  return __uint_as_float(u << 16);
}
__device__ __forceinline__ float bfhi(unsigned u) {   // high 16 bits -> float
  return __uint_as_float(u & 0xFFFF0000u);
}
__device__ __forceinline__ unsigned pack2(float a, float b) {
  return (unsigned)f2bf(a) | ((unsigned)f2bf(b) << 16);
}

// ---------- radix pass A1: per-(block,bucket) histogram ----------
__global__ __launch_bounds__(256) void histA_kernel(
    const int* __restrict__ dst, int* __restrict__ cnt) {
  __shared__ int h[NB];
  for (int i = threadIdx.x; i < NB; i += 256) h[i] = 0;
  __syncthreads();
  int start = blockIdx.x * EPB, end = start + EPB;
  for (int e = start + threadIdx.x; e < end; e += 256)
    atomicAdd(&h[dst[e] >> 8], 1);
  __syncthreads();
  for (int b = threadIdx.x; b < NB; b += 256)
    cnt[b * 256 + blockIdx.x] = h[b];   // bucket-major layout
}

// ---------- scan pass 1: per-block sums ----------
__global__ __launch_bounds__(256) void reduce_kernel(
    const int* __restrict__ cnt, int* __restrict__ partials) {
  __shared__ int s[256];
  int i = blockIdx.x * 256 + threadIdx.x;
  s[threadIdx.x] = cnt[i];
  __syncthreads();
  for (int off = 128; off > 0; off >>= 1) {
    if (threadIdx.x < off) s[threadIdx.x] += s[threadIdx.x + off];
    __syncthreads();
  }
  if (threadIdx.x == 0) partials[blockIdx.x] = s[0];
}

// ---------- scan pass 2: exclusive scan of NB partials (1 block) ----------
__global__ __launch_bounds__(256) void scanpart_kernel(int* __restrict__ partials) {
  __shared__ int s[NB];
  for (int i = threadIdx.x; i < NB; i += 256) s[i] = partials[i];
  __syncthreads();
  if (threadIdx.x == 0) {
    int run = 0;
    for (int i = 0; i < NB; ++i) { int v = s[i]; s[i] = run; run += v; }
  }
  __syncthreads();
  for (int i = threadIdx.x; i < NB; i += 256) partials[i] = s[i];
}

// ---------- scan pass 3: per-block exclusive scan + offset ----------
__global__ __launch_bounds__(256) void scanfinal_kernel(
    const int* __restrict__ cnt, const int* __restrict__ partials,
    int* __restrict__ scanned) {
  __shared__ int s[256];
  int t = threadIdx.x;
  int i = blockIdx.x * 256 + t;
  int c = cnt[i];
  s[t] = c;
  __syncthreads();
  for (int off = 1; off < 256; off <<= 1) {
    int v = (t >= off) ? s[t - off] : 0;
    __syncthreads();
    s[t] += v;
    __syncthreads();
  }
  scanned[i] = s[t] - c + partials[blockIdx.x];
}

// ---------- radix pass A2: partition packed edges into buckets ----------
__global__ __launch_bounds__(256) void partA_kernel(
    const int* __restrict__ src, const int* __restrict__ dst,
    const int* __restrict__ scanned, int* __restrict__ part) {
  __shared__ int cur[NB];
  for (int i = threadIdx.x; i < NB; i += 256)
    cur[i] = scanned[i * 256 + blockIdx.x];
  __syncthreads();
  int start = blockIdx.x * EPB, end = start + EPB;
  for (int e = start + threadIdx.x; e < end; e += 256) {
    int d = dst[e], s = src[e];
    int pos = atomicAdd(&cur[d >> 8], 1);
    part[pos] = ((d & 255) << 17) | s;
  }
}

// ---------- radix pass B: per-bucket CSR (row_start + eidx) ----------
__global__ __launch_bounds__(256) void bucket_csr_kernel(
    const int* __restrict__ part, const int* __restrict__ scanned,
    int* __restrict__ row_start, int* __restrict__ eidx) {
  int b = blockIdx.x, t = threadIdx.x;
  int ebeg = scanned[b * 256];
  int eend = (b == NB - 1) ? NE : scanned[(b + 1) * 256];
  int nbase = b << 8;
  int nloc = NN - nbase; if (nloc > 256) nloc = 256;
  __shared__ int cntL[256];
  __shared__ int exclL[256];
  cntL[t] = 0;
  __syncthreads();
  for (int e = ebeg + t; e < eend; e += 256)
    atomicAdd(&cntL[part[e] >> 17], 1);
  __syncthreads();
  int c = cntL[t];
  exclL[t] = c;
  __syncthreads();
  for (int off = 1; off < 256; off <<= 1) {
    int v = (t >= off) ? exclL[t - off] : 0;
    __syncthreads();
    exclL[t] += v;
    __syncthreads();
  }
  int excl = exclL[t] - c;
  if (t < nloc) row_start[nbase + t] = ebeg + excl;
  if (b == NB - 1 && t == 0) row_start[NN] = NE;
  cntL[t] = excl;                 // reuse as cursor
  __syncthreads();
  for (int e = ebeg + t; e < eend; e += 256) {
    int v = part[e];
    int pos = atomicAdd(&cntL[v >> 17], 1);
    eidx[ebeg + pos] = v & 0x1FFFF;
  }
}

// ---------- graph boundaries: batch is sorted -> binary search ----------
__global__ __launch_bounds__(256) void bounds_kernel(
    const int* __restrict__ batch, int* __restrict__ gs) {
  int g = blockIdx.x * 256 + threadIdx.x;
  if (g > NG) return;
  if (g == NG) { gs[NG] = NN; return; }
  int lo = 0, hi = NN;
  while (lo < hi) {
    int mid = (lo + hi) >> 1;
    if (batch[mid] < g) lo = mid + 1; else hi = mid;
  }
  gs[g] = lo;
}

// ---------- one-time bf16 hi/lo weight split into fragment image ----------
__global__ __launch_bounds__(256) void split_w_kernel(
    const float* __restrict__ W1l, const float* __restrict__ W1r,
    short* __restrict__ wfrag) {
  int i = blockIdx.x * 256 + threadIdx.x;
  if (i >= DIN * DH) return;
  int k = i >> 6, n = i & 63;
  int kt = k >> 5, kin = k & 31;
  int lane = ((kin >> 3) << 4) | (n & 15);
  int j8 = kin & 7;
  int jt = n >> 4;
  float wl = W1l[i], wr = W1r[i];
  unsigned bl_ = __float_as_uint(wl);
  unsigned br_ = __float_as_uint(wr);
  short hl = (short)(bl_ >> 16);
  short hr = (short)(br_ >> 16);
  float rl = wl - __uint_as_float(bl_ & 0xFFFF0000u);
  float rr = wr - __uint_as_float(br_ & 0xFFFF0000u);
  short ll = (short)(__float_as_uint(rl) >> 16);
  short lr = (short)(__float_as_uint(rr) >> 16);
  int base0 = (((kt * 2 + 0) * 4 + jt) * 2) * 512 + lane * 8 + j8;
  int base1 = (((kt * 2 + 1) * 4 + jt) * 2) * 512 + lane * 8 + j8;
  wfrag[base0]       = hl;
  wfrag[base0 + 512] = ll;
  wfrag[base1]       = hr;
  wfrag[base1 + 512] = lr;
}

// ---------- fused projection (MFMA): xl(bf16) = x@W1l, xr(f32) = x@W1r+b1 ----------
__global__ __launch_bounds__(256) void proj_mfma_kernel(
    const float* __restrict__ x, const short* __restrict__ wfrag,
    const float* __restrict__ b1, unsigned short* __restrict__ xlb,
    float* __restrict__ xr) {
  __shared__ short sB[32768];   // 64 KB
  {
    const float4* wf4 = (const float4*)wfrag;
    float4* sB4 = (float4*)sB;
    for (int i = threadIdx.x; i < 4096; i += 256) sB4[i] = wf4[i];
  }
  __syncthreads();

  int wave = threadIdx.x >> 6;
  int lane = threadIdx.x & 63;
  int m = lane & 15, q = lane >> 4;
  int tpair = blockIdx.x * 4 + wave;
  int tile0 = tpair * 2, tile1 = tile0 + 1;
  if (tile0 >= 6250) return;

  int r0 = tile0 * 16 + m;
  int r1 = tile1 * 16 + m; if (r1 > NN - 1) r1 = NN - 1;
  const float4* xa = (const float4*)x + (size_t)r0 * 32 + q * 2;
  const float4* xb = (const float4*)x + (size_t)r1 * 32 + q * 2;

  floatx4 acc0[8], acc1[8];
#pragma unroll
  for (int a = 0; a < 8; ++a) {
    acc0[a] = (floatx4){0.f, 0.f, 0.f, 0.f};
    acc1[a] = (floatx4){0.f, 0.f, 0.f, 0.f};
  }

#pragma unroll
  for (int kt = 0; kt < 4; ++kt) {
    float4 p0 = xa[kt * 8];
    float4 p1 = xa[kt * 8 + 1];
    float4 p2 = xb[kt * 8];
    float4 p3 = xb[kt * 8 + 1];
    float af0[8] = {p0.x, p0.y, p0.z, p0.w, p1.x, p1.y, p1.z, p1.w};
    float af1[8] = {p2.x, p2.y, p2.z, p2.w, p3.x, p3.y, p3.z, p3.w};
    short8 ah0, al0, ah1, al1;
#pragma unroll
    for (int e = 0; e < 8; ++e) {
      unsigned b0 = __float_as_uint(af0[e]);
      ah0[e] = (short)(b0 >> 16);
      float lo0 = af0[e] - __uint_as_float(b0 & 0xFFFF0000u);
      al0[e] = (short)(__float_as_uint(lo0) >> 16);
      unsigned b1_ = __float_as_uint(af1[e]);
      ah1[e] = (short)(b1_ >> 16);
      float lo1 = af1[e] - __uint_as_float(b1_ & 0xFFFF0000u);
      al1[e] = (short)(__float_as_uint(lo1) >> 16);
    }
#pragma unroll
    for (int mat = 0; mat < 2; ++mat) {
#pragma unroll
      for (int jt = 0; jt < 4; ++jt) {
        int unit = ((kt * 2 + mat) * 4 + jt) * 2;
        short8 bh = *(const short8*)(sB + unit * 512 + lane * 8);
        short8 bl = *(const short8*)(sB + (unit + 1) * 512 + lane * 8);
        floatx4 c0 = acc0[mat * 4 + jt];
        c0 = __builtin_amdgcn_mfma_f32_16x16x32_bf16(ah0, bh, c0, 0, 0, 0);
        c0 = __builtin_amdgcn_mfma_f32_16x16x32_bf16(ah0, bl, c0, 0, 0, 0);
        c0 = __builtin_amdgcn_mfma_f32_16x16x32_bf16(al0, bh, c0, 0, 0, 0);
        acc0[mat * 4 + jt] = c0;
        floatx4 c1 = acc1[mat * 4 + jt];
        c1 = __builtin_amdgcn_mfma_f32_16x16x32_bf16(ah1, bh, c1, 0, 0, 0);
        c1 = __builtin_amdgcn_mfma_f32_16x16x32_bf16(ah1, bl, c1, 0, 0, 0);
        c1 = __builtin_amdgcn_mfma_f32_16x16x32_bf16(al1, bh, c1, 0, 0, 0);
        acc1[mat * 4 + jt] = c1;
      }
    }
  }

#pragma unroll
  for (int jt = 0; jt < 4; ++jt) {
    int j = jt * 16 + m;
    float bj = b1[j];
    floatx4 cl0 = acc0[jt], cr0 = acc0[4 + jt];
    floatx4 cl1 = acc1[jt], cr1 = acc1[4 + jt];
#pragma unroll
    for (int r = 0; r < 4; ++r) {
      int n0 = tile0 * 16 + q * 4 + r;
      xlb[(size_t)n0 * DH + j] = f2bf(cl0[r]);
      xr[(size_t)n0 * DH + j] = cr0[r] + bj;
    }
    if (tile1 < 6250) {
#pragma unroll
      for (int r = 0; r < 4; ++r) {
        int n1 = tile1 * 16 + q * 4 + r;
        xlb[(size_t)n1 * DH + j] = f2bf(cl1[r]);
        xr[(size_t)n1 * DH + j] = cr1[r] + bj;
      }
    }
  }
}

// ---------- mean aggregation via gather (bf16 rows, 16 lanes x uint2/node) ----------
// RELU_ADD: out = bf16(relu(mean + xr));  else: out = bf16(mean)
template <bool RELU_ADD>
__global__ __launch_bounds__(256) void gather_kernel(
    const uint2* __restrict__ feat2, const int* __restrict__ row_start,
    const int* __restrict__ eidx, const float4* __restrict__ xr4,
    uint2* __restrict__ out2) {
  int t = blockIdx.x * 256 + threadIdx.x;
  int node = t >> 4;
  if (node >= NN) return;
  int fl = t & 15;
  int rs = row_start[node], re = row_start[node + 1];
  float a0 = 0.f, a1 = 0.f, a2 = 0.f, a3 = 0.f;
  int k = rs;
  for (; k + 8 <= re; k += 8) {           // 8 uint2 loads in flight
    uint2 v[8];
#pragma unroll
    for (int u = 0; u < 8; ++u) v[u] = feat2[(size_t)eidx[k + u] * 16 + fl];
#pragma unroll
    for (int u = 0; u < 8; ++u) {
      a0 += bflo(v[u].x); a1 += bfhi(v[u].x);
      a2 += bflo(v[u].y); a3 += bfhi(v[u].y);
    }
  }
  for (; k + 2 <= re; k += 2) {
    uint2 v0 = feat2[(size_t)eidx[k] * 16 + fl];
    uint2 v1 = feat2[(size_t)eidx[k + 1] * 16 + fl];
    a0 += bflo(v0.x) + bflo(v1.x); a1 += bfhi(v0.x) + bfhi(v1.x);
    a2 += bflo(v0.y) + bflo(v1.y); a3 += bfhi(v0.y) + bfhi(v1.y);
  }
  if (k < re) {
    uint2 v = feat2[(size_t)eidx[k] * 16 + fl];
    a0 += bflo(v.x); a1 += bfhi(v.x);
    a2 += bflo(v.y); a3 += bfhi(v.y);
  }
  float inv = 1.0f / fmaxf((float)(re - rs), 1.0f);
  a0 *= inv; a1 *= inv; a2 *= inv; a3 *= inv;
  if (RELU_ADD) {
    float4 r = xr4[(size_t)node * 16 + fl];
    a0 = fmaxf(a0 + r.x, 0.f); a1 = fmaxf(a1 + r.y, 0.f);
    a2 = fmaxf(a2 + r.z, 0.f); a3 = fmaxf(a3 + r.w, 0.f);
  }
  uint2 o;
  o.x = pack2(a0, a1);
  o.y = pack2(a2, a3);
  out2[(size_t)node * 16 + fl] = o;
}

// ---------- per-graph segment-sum of h(bf16) and mean2(bf16) ----------
__global__ __launch_bounds__(256) void pool_kernel(
    const unsigned short* __restrict__ hb, const unsigned short* __restrict__ mb,
    const int* __restrict__ gs, float* __restrict__ hs,
    float* __restrict__ ms) {
  int g = blockIdx.x;
  int start = gs[g], end = gs[g + 1];
  int slot = threadIdx.x >> 6, j = threadIdx.x & 63;
  float sh = 0.f, sm = 0.f;
  for (int n = start + slot; n < end; n += 4) {
    sh += bflo((unsigned)hb[(size_t)n * DH + j]);
    sm += bflo((unsigned)mb[(size_t)n * DH + j]);
  }
  __shared__ float red[2][4][DH];
  red[0][slot][j] = sh;
  red[1][slot][j] = sm;
  __syncthreads();
  if (slot == 0) {
    sh = red[0][0][j] + red[0][1][j] + red[0][2][j] + red[0][3][j];
    sm = red[1][0][j] + red[1][1][j] + red[1][2][j] + red[1][3][j];
    hs[g * DH + j] = sh;
    ms[g * DH + j] = sm;
  }
}

// ---------- final tiny matmul ----------
__global__ __launch_bounds__(128) void final_kernel(
    const float* __restrict__ hs, const float* __restrict__ ms,
    const float* __restrict__ W2l, const float* __restrict__ W2r,
    const float* __restrict__ b2, const int* __restrict__ gs,
    float* __restrict__ out) {
  int g = blockIdx.x;
  int j = threadIdx.x;
  float n = (float)(gs[g + 1] - gs[g]);
  float acc = 0.f;
#pragma unroll 8
  for (int k = 0; k < DH; ++k)
    acc += ms[g * DH + k] * W2l[k * DOUT + j] + hs[g * DH + k] * W2r[k * DOUT + j];
  float inv = 1.0f / fmaxf(n, 1.0f);
  out[g * DOUT + j] = (acc + n * b2[j]) * inv;
}

extern "C" void kernel_launch(void* const* d_in, const int* in_sizes, int n_in,
                              void* d_out, int out_size, void* d_ws, size_t ws_size,
                              hipStream_t stream) {
  (void)in_sizes; (void)n_in; (void)out_size; (void)ws_size;
  const float* x   = (const float*)d_in[0];
  const float* W1l = (const float*)d_in[1];
  const float* W1r = (const float*)d_in[2];
  const float* b1  = (const float*)d_in[3];
  const float* W2l = (const float*)d_in[4];
  const float* W2r = (const float*)d_in[5];
  const float* b2  = (const float*)d_in[6];
  const int*   ei  = (const int*)d_in[7];
  const int*   batch = (const int*)d_in[8];
  const int* src = ei;            // edge_index[0, :]
  const int* dst = ei + NE;       // edge_index[1, :]
  float* out = (float*)d_out;

  char* ws = (char*)d_ws;
  unsigned short* xlb = (unsigned short*)(ws);            // 12,800,000 B
  unsigned short* hb  = (unsigned short*)(ws + 12800000); // 12,800,000 B
  unsigned short* mb  = (unsigned short*)(ws + 25600000); // 12,800,000 B
  // CSR-build scratch overlays the xr region (all dead before proj writes xr)
  int*  part      = (int*)(ws + 51200000);           //  6,400,000 B
  int*  cnt       = (int*)(ws + 57600000);           //    400,384 B (MSZ)
  int*  scanned   = (int*)(ws + 58000384);           //    400,384 B (MSZ)
  float* xr       = (float*)(ws + 51200000);         // 25,600,000 B (-> 76.8M)
  int*  eidx      = (int*)(ws + 76800000);           //  6,400,000 B
  int*  row_start = (int*)(ws + 83200000);           //    400,004 B
  int*   gs       = (int*)(ws + 83600128);           //      2,052 B
  float* hs       = (float*)(ws + 83604224);         //    131,072 B
  float* msum     = (float*)(ws + 83735296);         //    131,072 B
  short* wfrag    = (short*)(ws + 83900032);         //     65,536 B
  int*  partials  = (int*)(ws + 84400128);           //      1,564 B

  const int gBlocks = (NN * 16) / 256;               // 6250
  const int pBlocks = 782;                           // ceil(3125 pairs / 4 waves)

  // bucket-radix CSR build + weight split (independent)
  split_w_kernel<<<32, 256, 0, stream>>>(W1l, W1r, wfrag);
  histA_kernel<<<256, 256, 0, stream>>>(dst, cnt);
  reduce_kernel<<<NB, 256, 0, stream>>>(cnt, partials);
  scanpart_kernel<<<1, 256, 0, stream>>>(partials);
  scanfinal_kernel<<<NB, 256, 0, stream>>>(cnt, partials, scanned);
  partA_kernel<<<256, 256, 0, stream>>>(src, dst, scanned, part);
  bucket_csr_kernel<<<NB, 256, 0, stream>>>(part, scanned, row_start, eidx);
  bounds_kernel<<<3, 256, 0, stream>>>(batch, gs);

  // layer 1
  proj_mfma_kernel<<<pBlocks, 256, 0, stream>>>(x, wfrag, b1, xlb, xr);
  gather_kernel<true><<<gBlocks, 256, 0, stream>>>(
      (const uint2*)xlb, row_start, eidx, (const float4*)xr, (uint2*)hb);

  // layer 2 aggregation
  gather_kernel<false><<<gBlocks, 256, 0, stream>>>(
      (const uint2*)hb, row_start, eidx, nullptr, (uint2*)mb);

  // pool-then-matmul
  pool_kernel<<<NG, 256, 0, stream>>>(hb, mb, gs, hs, msum);
  final_kernel<<<NG, 128, 0, stream>>>(hs, msum, W2l, W2r, b2, gs, out);
}

// Round 13
// 252.758 us; speedup vs baseline: 1.5314x; 1.0533x over previous
//
#include <hip/hip_runtime.h>

#define NN   100000
#define NE   1600000
#define DIN  128
#define DH   64
#define DOUT 128
#define NG   512

#define NB   391     // dst buckets of 256 nodes: ceil(NN/256)
#define EPB  6250    // edges per partition block: NE/256
#define MSZ  (NB*256) // 100,096 — scan length

typedef short short8 __attribute__((ext_vector_type(8)));
typedef float floatx4 __attribute__((ext_vector_type(4)));

__device__ __forceinline__ unsigned short f2bf(float f) {
  unsigned b = __float_as_uint(f);
  b += 0x7FFF + ((b >> 16) & 1);          // round-to-nearest-even
  return (unsigned short)(b >> 16);
}
__device__ __forceinline__ float bflo(unsigned u) {   // low 16 bits -> float
  return __uint_as_float(u << 16);
}
__device__ __forceinline__ float bfhi(unsigned u) {   // high 16 bits -> float
  return __uint_as_float(u & 0xFFFF0000u);
}
__device__ __forceinline__ unsigned pack2(float a, float b) {
  return (unsigned)f2bf(a) | ((unsigned)f2bf(b) << 16);
}

// ---------- radix pass A1: per-(block,bucket) histogram ----------
__global__ __launch_bounds__(256) void histA_kernel(
    const int* __restrict__ dst, int* __restrict__ cnt) {
  __shared__ int h[NB];
  for (int i = threadIdx.x; i < NB; i += 256) h[i] = 0;
  __syncthreads();
  int start = blockIdx.x * EPB, end = start + EPB;
  for (int e = start + threadIdx.x; e < end; e += 256)
    atomicAdd(&h[dst[e] >> 8], 1);
  __syncthreads();
  for (int b = threadIdx.x; b < NB; b += 256)
    cnt[b * 256 + blockIdx.x] = h[b];   // bucket-major layout
}

// ---------- scan pass 1: per-block sums ----------
__global__ __launch_bounds__(256) void reduce_kernel(
    const int* __restrict__ cnt, int* __restrict__ partials) {
  __shared__ int s[256];
  int i = blockIdx.x * 256 + threadIdx.x;
  s[threadIdx.x] = cnt[i];
  __syncthreads();
  for (int off = 128; off > 0; off >>= 1) {
    if (threadIdx.x < off) s[threadIdx.x] += s[threadIdx.x + off];
    __syncthreads();
  }
  if (threadIdx.x == 0) partials[blockIdx.x] = s[0];
}

// ---------- scan pass 2: exclusive scan of NB partials (1 block) ----------
__global__ __launch_bounds__(256) void scanpart_kernel(int* __restrict__ partials) {
  __shared__ int s[NB];
  for (int i = threadIdx.x; i < NB; i += 256) s[i] = partials[i];
  __syncthreads();
  if (threadIdx.x == 0) {
    int run = 0;
    for (int i = 0; i < NB; ++i) { int v = s[i]; s[i] = run; run += v; }
  }
  __syncthreads();
  for (int i = threadIdx.x; i < NB; i += 256) partials[i] = s[i];
}

// ---------- scan pass 3: per-block exclusive scan + offset ----------
__global__ __launch_bounds__(256) void scanfinal_kernel(
    const int* __restrict__ cnt, const int* __restrict__ partials,
    int* __restrict__ scanned) {
  __shared__ int s[256];
  int t = threadIdx.x;
  int i = blockIdx.x * 256 + t;
  int c = cnt[i];
  s[t] = c;
  __syncthreads();
  for (int off = 1; off < 256; off <<= 1) {
    int v = (t >= off) ? s[t - off] : 0;
    __syncthreads();
    s[t] += v;
    __syncthreads();
  }
  scanned[i] = s[t] - c + partials[blockIdx.x];
}

// ---------- radix pass A2: partition packed edges into buckets ----------
__global__ __launch_bounds__(256) void partA_kernel(
    const int* __restrict__ src, const int* __restrict__ dst,
    const int* __restrict__ scanned, int* __restrict__ part) {
  __shared__ int cur[NB];
  for (int i = threadIdx.x; i < NB; i += 256)
    cur[i] = scanned[i * 256 + blockIdx.x];
  __syncthreads();
  int start = blockIdx.x * EPB, end = start + EPB;
  for (int e = start + threadIdx.x; e < end; e += 256) {
    int d = dst[e], s = src[e];
    int pos = atomicAdd(&cur[d >> 8], 1);
    part[pos] = ((d & 255) << 17) | s;
  }
}

// ---------- radix pass B: per-bucket CSR (row_start + eidx) ----------
__global__ __launch_bounds__(256) void bucket_csr_kernel(
    const int* __restrict__ part, const int* __restrict__ scanned,
    int* __restrict__ row_start, int* __restrict__ eidx) {
  int b = blockIdx.x, t = threadIdx.x;
  int ebeg = scanned[b * 256];
  int eend = (b == NB - 1) ? NE : scanned[(b + 1) * 256];
  int nbase = b << 8;
  int nloc = NN - nbase; if (nloc > 256) nloc = 256;
  __shared__ int cntL[256];
  __shared__ int exclL[256];
  cntL[t] = 0;
  __syncthreads();
  for (int e = ebeg + t; e < eend; e += 256)
    atomicAdd(&cntL[part[e] >> 17], 1);
  __syncthreads();
  int c = cntL[t];
  exclL[t] = c;
  __syncthreads();
  for (int off = 1; off < 256; off <<= 1) {
    int v = (t >= off) ? exclL[t - off] : 0;
    __syncthreads();
    exclL[t] += v;
    __syncthreads();
  }
  int excl = exclL[t] - c;
  if (t < nloc) row_start[nbase + t] = ebeg + excl;
  if (b == NB - 1 && t == 0) row_start[NN] = NE;
  cntL[t] = excl;                 // reuse as cursor
  __syncthreads();
  for (int e = ebeg + t; e < eend; e += 256) {
    int v = part[e];
    int pos = atomicAdd(&cntL[v >> 17], 1);
    eidx[ebeg + pos] = v & 0x1FFFF;
  }
}

// ---------- graph boundaries: batch is sorted -> binary search ----------
__global__ __launch_bounds__(256) void bounds_kernel(
    const int* __restrict__ batch, int* __restrict__ gs) {
  int g = blockIdx.x * 256 + threadIdx.x;
  if (g > NG) return;
  if (g == NG) { gs[NG] = NN; return; }
  int lo = 0, hi = NN;
  while (lo < hi) {
    int mid = (lo + hi) >> 1;
    if (batch[mid] < g) lo = mid + 1; else hi = mid;
  }
  gs[g] = lo;
}

// ---------- one-time bf16 hi/lo weight split into fragment image ----------
__global__ __launch_bounds__(256) void split_w_kernel(
    const float* __restrict__ W1l, const float* __restrict__ W1r,
    short* __restrict__ wfrag) {
  int i = blockIdx.x * 256 + threadIdx.x;
  if (i >= DIN * DH) return;
  int k = i >> 6, n = i & 63;
  int kt = k >> 5, kin = k & 31;
  int lane = ((kin >> 3) << 4) | (n & 15);
  int j8 = kin & 7;
  int jt = n >> 4;
  float wl = W1l[i], wr = W1r[i];
  unsigned bl_ = __float_as_uint(wl);
  unsigned br_ = __float_as_uint(wr);
  short hl = (short)(bl_ >> 16);
  short hr = (short)(br_ >> 16);
  float rl = wl - __uint_as_float(bl_ & 0xFFFF0000u);
  float rr = wr - __uint_as_float(br_ & 0xFFFF0000u);
  short ll = (short)(__float_as_uint(rl) >> 16);
  short lr = (short)(__float_as_uint(rr) >> 16);
  int base0 = (((kt * 2 + 0) * 4 + jt) * 2) * 512 + lane * 8 + j8;
  int base1 = (((kt * 2 + 1) * 4 + jt) * 2) * 512 + lane * 8 + j8;
  wfrag[base0]       = hl;
  wfrag[base0 + 512] = ll;
  wfrag[base1]       = hr;
  wfrag[base1 + 512] = lr;
}

// ---------- fused projection (MFMA): xl(bf16)=x@W1l, xr(bf16)=x@W1r+b1 ----------
__global__ __launch_bounds__(256) void proj_mfma_kernel(
    const float* __restrict__ x, const short* __restrict__ wfrag,
    const float* __restrict__ b1, unsigned short* __restrict__ xlb,
    unsigned short* __restrict__ xrb) {
  __shared__ short sB[32768];   // 64 KB
  {
    const float4* wf4 = (const float4*)wfrag;
    float4* sB4 = (float4*)sB;
    for (int i = threadIdx.x; i < 4096; i += 256) sB4[i] = wf4[i];
  }
  __syncthreads();

  int wave = threadIdx.x >> 6;
  int lane = threadIdx.x & 63;
  int m = lane & 15, q = lane >> 4;
  int tpair = blockIdx.x * 4 + wave;
  int tile0 = tpair * 2, tile1 = tile0 + 1;
  if (tile0 >= 6250) return;

  int r0 = tile0 * 16 + m;
  int r1 = tile1 * 16 + m; if (r1 > NN - 1) r1 = NN - 1;
  const float4* xa = (const float4*)x + (size_t)r0 * 32 + q * 2;
  const float4* xb = (const float4*)x + (size_t)r1 * 32 + q * 2;

  floatx4 acc0[8], acc1[8];
#pragma unroll
  for (int a = 0; a < 8; ++a) {
    acc0[a] = (floatx4){0.f, 0.f, 0.f, 0.f};
    acc1[a] = (floatx4){0.f, 0.f, 0.f, 0.f};
  }

#pragma unroll
  for (int kt = 0; kt < 4; ++kt) {
    float4 p0 = xa[kt * 8];
    float4 p1 = xa[kt * 8 + 1];
    float4 p2 = xb[kt * 8];
    float4 p3 = xb[kt * 8 + 1];
    float af0[8] = {p0.x, p0.y, p0.z, p0.w, p1.x, p1.y, p1.z, p1.w};
    float af1[8] = {p2.x, p2.y, p2.z, p2.w, p3.x, p3.y, p3.z, p3.w};
    short8 ah0, al0, ah1, al1;
#pragma unroll
    for (int e = 0; e < 8; ++e) {
      unsigned b0 = __float_as_uint(af0[e]);
      ah0[e] = (short)(b0 >> 16);
      float lo0 = af0[e] - __uint_as_float(b0 & 0xFFFF0000u);
      al0[e] = (short)(__float_as_uint(lo0) >> 16);
      unsigned b1_ = __float_as_uint(af1[e]);
      ah1[e] = (short)(b1_ >> 16);
      float lo1 = af1[e] - __uint_as_float(b1_ & 0xFFFF0000u);
      al1[e] = (short)(__float_as_uint(lo1) >> 16);
    }
#pragma unroll
    for (int mat = 0; mat < 2; ++mat) {
#pragma unroll
      for (int jt = 0; jt < 4; ++jt) {
        int unit = ((kt * 2 + mat) * 4 + jt) * 2;
        short8 bh = *(const short8*)(sB + unit * 512 + lane * 8);
        short8 bl = *(const short8*)(sB + (unit + 1) * 512 + lane * 8);
        floatx4 c0 = acc0[mat * 4 + jt];
        c0 = __builtin_amdgcn_mfma_f32_16x16x32_bf16(ah0, bh, c0, 0, 0, 0);
        c0 = __builtin_amdgcn_mfma_f32_16x16x32_bf16(ah0, bl, c0, 0, 0, 0);
        c0 = __builtin_amdgcn_mfma_f32_16x16x32_bf16(al0, bh, c0, 0, 0, 0);
        acc0[mat * 4 + jt] = c0;
        floatx4 c1 = acc1[mat * 4 + jt];
        c1 = __builtin_amdgcn_mfma_f32_16x16x32_bf16(ah1, bh, c1, 0, 0, 0);
        c1 = __builtin_amdgcn_mfma_f32_16x16x32_bf16(ah1, bl, c1, 0, 0, 0);
        c1 = __builtin_amdgcn_mfma_f32_16x16x32_bf16(al1, bh, c1, 0, 0, 0);
        acc1[mat * 4 + jt] = c1;
      }
    }
  }

#pragma unroll
  for (int jt = 0; jt < 4; ++jt) {
    int j = jt * 16 + m;
    float bj = b1[j];
    floatx4 cl0 = acc0[jt], cr0 = acc0[4 + jt];
    floatx4 cl1 = acc1[jt], cr1 = acc1[4 + jt];
#pragma unroll
    for (int r = 0; r < 4; ++r) {
      int n0 = tile0 * 16 + q * 4 + r;
      xlb[(size_t)n0 * DH + j] = f2bf(cl0[r]);
      xrb[(size_t)n0 * DH + j] = f2bf(cr0[r] + bj);
    }
    if (tile1 < 6250) {
#pragma unroll
      for (int r = 0; r < 4; ++r) {
        int n1 = tile1 * 16 + q * 4 + r;
        xlb[(size_t)n1 * DH + j] = f2bf(cl1[r]);
        xrb[(size_t)n1 * DH + j] = f2bf(cr1[r] + bj);
      }
    }
  }
}

// ---------- mean aggregation via gather (bf16 rows, 8 lanes x uint4/node) ----------
// RELU_ADD: out = bf16(relu(mean + xr));  else: out = bf16(mean)
template <bool RELU_ADD>
__global__ __launch_bounds__(256) void gather_kernel(
    const uint4* __restrict__ feat4, const int* __restrict__ row_start,
    const int* __restrict__ eidx, const uint4* __restrict__ xr4,
    uint4* __restrict__ out4) {
  int t = blockIdx.x * 256 + threadIdx.x;
  int node = t >> 3;
  if (node >= NN) return;
  int fl = t & 7;
  int rs = row_start[node], re = row_start[node + 1];
  float a0 = 0.f, a1 = 0.f, a2 = 0.f, a3 = 0.f;
  float a4 = 0.f, a5 = 0.f, a6 = 0.f, a7 = 0.f;
  int k = rs;
  for (; k + 8 <= re; k += 8) {           // 8 uint4 loads in flight
    uint4 v[8];
#pragma unroll
    for (int u = 0; u < 8; ++u) v[u] = feat4[(size_t)eidx[k + u] * 8 + fl];
#pragma unroll
    for (int u = 0; u < 8; ++u) {
      a0 += bflo(v[u].x); a1 += bfhi(v[u].x);
      a2 += bflo(v[u].y); a3 += bfhi(v[u].y);
      a4 += bflo(v[u].z); a5 += bfhi(v[u].z);
      a6 += bflo(v[u].w); a7 += bfhi(v[u].w);
    }
  }
  for (; k + 2 <= re; k += 2) {
    uint4 v0 = feat4[(size_t)eidx[k] * 8 + fl];
    uint4 v1 = feat4[(size_t)eidx[k + 1] * 8 + fl];
    a0 += bflo(v0.x) + bflo(v1.x); a1 += bfhi(v0.x) + bfhi(v1.x);
    a2 += bflo(v0.y) + bflo(v1.y); a3 += bfhi(v0.y) + bfhi(v1.y);
    a4 += bflo(v0.z) + bflo(v1.z); a5 += bfhi(v0.z) + bfhi(v1.z);
    a6 += bflo(v0.w) + bflo(v1.w); a7 += bfhi(v0.w) + bfhi(v1.w);
  }
  if (k < re) {
    uint4 v = feat4[(size_t)eidx[k] * 8 + fl];
    a0 += bflo(v.x); a1 += bfhi(v.x);
    a2 += bflo(v.y); a3 += bfhi(v.y);
    a4 += bflo(v.z); a5 += bfhi(v.z);
    a6 += bflo(v.w); a7 += bfhi(v.w);
  }
  float inv = 1.0f / fmaxf((float)(re - rs), 1.0f);
  a0 *= inv; a1 *= inv; a2 *= inv; a3 *= inv;
  a4 *= inv; a5 *= inv; a6 *= inv; a7 *= inv;
  if (RELU_ADD) {
    uint4 r = xr4[(size_t)node * 8 + fl];
    a0 = fmaxf(a0 + bflo(r.x), 0.f); a1 = fmaxf(a1 + bfhi(r.x), 0.f);
    a2 = fmaxf(a2 + bflo(r.y), 0.f); a3 = fmaxf(a3 + bfhi(r.y), 0.f);
    a4 = fmaxf(a4 + bflo(r.z), 0.f); a5 = fmaxf(a5 + bfhi(r.z), 0.f);
    a6 = fmaxf(a6 + bflo(r.w), 0.f); a7 = fmaxf(a7 + bfhi(r.w), 0.f);
  }
  uint4 o;
  o.x = pack2(a0, a1);
  o.y = pack2(a2, a3);
  o.z = pack2(a4, a5);
  o.w = pack2(a6, a7);
  out4[(size_t)node * 8 + fl] = o;
}

// ---------- fused pool + final matmul: one block per graph ----------
__global__ __launch_bounds__(256) void pool_final_kernel(
    const unsigned* __restrict__ hb2, const unsigned* __restrict__ mb2,
    const int* __restrict__ gs, const float* __restrict__ W2l,
    const float* __restrict__ W2r, const float* __restrict__ b2,
    float* __restrict__ out) {
  int g = blockIdx.x;
  int start = gs[g], end = gs[g + 1];
  int slot = threadIdx.x >> 5;        // 0..7
  int j2   = threadIdx.x & 31;        // uint index (2 feats)
  float sh0 = 0.f, sh1 = 0.f, sm0 = 0.f, sm1 = 0.f;
  for (int n = start + slot; n < end; n += 8) {
    unsigned hv = hb2[(size_t)n * 32 + j2];
    unsigned mv = mb2[(size_t)n * 32 + j2];
    sh0 += bflo(hv); sh1 += bfhi(hv);
    sm0 += bflo(mv); sm1 += bfhi(mv);
  }
  __shared__ float redh[8][DH];
  __shared__ float redm[8][DH];
  redh[slot][j2 * 2] = sh0; redh[slot][j2 * 2 + 1] = sh1;
  redm[slot][j2 * 2] = sm0; redm[slot][j2 * 2 + 1] = sm1;
  __syncthreads();
  __shared__ float hsL[DH], msL[DH];
  if (threadIdx.x < DH) {
    float a = 0.f, b = 0.f;
#pragma unroll
    for (int s = 0; s < 8; ++s) { a += redh[s][threadIdx.x]; b += redm[s][threadIdx.x]; }
    hsL[threadIdx.x] = a; msL[threadIdx.x] = b;
  }
  __syncthreads();
  int j = threadIdx.x;
  if (j < DOUT) {
    float n = (float)(end - start);
    float acc = 0.f;
#pragma unroll 8
    for (int k = 0; k < DH; ++k)
      acc += msL[k] * W2l[k * DOUT + j] + hsL[k] * W2r[k * DOUT + j];
    out[g * DOUT + j] = (acc + n * b2[j]) / fmaxf(n, 1.0f);
  }
}

extern "C" void kernel_launch(void* const* d_in, const int* in_sizes, int n_in,
                              void* d_out, int out_size, void* d_ws, size_t ws_size,
                              hipStream_t stream) {
  (void)in_sizes; (void)n_in; (void)out_size; (void)ws_size;
  const float* x   = (const float*)d_in[0];
  const float* W1l = (const float*)d_in[1];
  const float* W1r = (const float*)d_in[2];
  const float* b1  = (const float*)d_in[3];
  const float* W2l = (const float*)d_in[4];
  const float* W2r = (const float*)d_in[5];
  const float* b2  = (const float*)d_in[6];
  const int*   ei  = (const int*)d_in[7];
  const int*   batch = (const int*)d_in[8];
  const int* src = ei;            // edge_index[0, :]
  const int* dst = ei + NE;       // edge_index[1, :]
  float* out = (float*)d_out;

  char* ws = (char*)d_ws;
  unsigned short* xlb = (unsigned short*)(ws);            // 12,800,000 B
  unsigned short* hb  = (unsigned short*)(ws + 12800000); // 12,800,000 B
  unsigned short* mb  = (unsigned short*)(ws + 25600000); // 12,800,000 B
  unsigned short* xrb = (unsigned short*)(ws + 38400000); // 12,800,000 B
  int*  part      = (int*)(ws + 51200000);           //  6,400,000 B
  int*  cnt       = (int*)(ws + 57600000);           //    400,384 B (MSZ)
  int*  scanned   = (int*)(ws + 58000384);           //    400,384 B (MSZ)
  int*  eidx      = (int*)(ws + 76800000);           //  6,400,000 B
  int*  row_start = (int*)(ws + 83200000);           //    400,004 B
  int*   gs       = (int*)(ws + 83600128);           //      2,052 B
  short* wfrag    = (short*)(ws + 83900032);         //     65,536 B
  int*  partials  = (int*)(ws + 84400128);           //      1,564 B

  const int gBlocks = (NN * 8 + 255) / 256;          // 3125
  const int pBlocks = 782;                           // ceil(3125 pairs / 4 waves)

  // bucket-radix CSR build + weight split (independent)
  split_w_kernel<<<32, 256, 0, stream>>>(W1l, W1r, wfrag);
  histA_kernel<<<256, 256, 0, stream>>>(dst, cnt);
  reduce_kernel<<<NB, 256, 0, stream>>>(cnt, partials);
  scanpart_kernel<<<1, 256, 0, stream>>>(partials);
  scanfinal_kernel<<<NB, 256, 0, stream>>>(cnt, partials, scanned);
  partA_kernel<<<256, 256, 0, stream>>>(src, dst, scanned, part);
  bucket_csr_kernel<<<NB, 256, 0, stream>>>(part, scanned, row_start, eidx);
  bounds_kernel<<<3, 256, 0, stream>>>(batch, gs);

  // layer 1
  proj_mfma_kernel<<<pBlocks, 256, 0, stream>>>(x, wfrag, b1, xlb, xrb);
  gather_kernel<true><<<gBlocks, 256, 0, stream>>>(
      (const uint4*)xlb, row_start, eidx, (const uint4*)xrb, (uint4*)hb);

  // layer 2 aggregation
  gather_kernel<false><<<gBlocks, 256, 0, stream>>>(
      (const uint4*)hb, row_start, eidx, nullptr, (uint4*)mb);

  // fused pool + final matmul
  pool_final_kernel<<<NG, 256, 0, stream>>>(
      (const unsigned*)hb, (const unsigned*)mb, gs, W2l, W2r, b2, out);
}

// Round 14
// 247.429 us; speedup vs baseline: 1.5644x; 1.0215x over previous
//
#include <hip/hip_runtime.h>

#define NN   100000
#define NE   1600000
#define DIN  128
#define DH   64
#define DOUT 128
#define NG   512

#define NB   391     // dst buckets of 256 nodes: ceil(NN/256)
#define EPB  6250    // edges per partition block: NE/256
#define MSZ  (NB*256) // 100,096 — scan length

typedef short short8 __attribute__((ext_vector_type(8)));
typedef float floatx4 __attribute__((ext_vector_type(4)));

__device__ __forceinline__ unsigned short f2bf(float f) {
  unsigned b = __float_as_uint(f);
  b += 0x7FFF + ((b >> 16) & 1);          // round-to-nearest-even
  return (unsigned short)(b >> 16);
}
__device__ __forceinline__ float bflo(unsigned u) {   // low 16 bits -> float
  return __uint_as_float(u << 16);
}
__device__ __forceinline__ float bfhi(unsigned u) {   // high 16 bits -> float
  return __uint_as_float(u & 0xFFFF0000u);
}
__device__ __forceinline__ unsigned pack2(float a, float b) {
  return (unsigned)f2bf(a) | ((unsigned)f2bf(b) << 16);
}

// ---------- fused prep: histA (blocks 0..255) + split_w (256) + bounds (257) ----------
__global__ __launch_bounds__(256) void prep_kernel(
    const int* __restrict__ dst, int* __restrict__ cnt,
    const float* __restrict__ W1l, const float* __restrict__ W1r,
    short* __restrict__ wfrag, const int* __restrict__ batch,
    int* __restrict__ gs) {
  __shared__ int h[NB];
  int b = blockIdx.x;
  if (b < 256) {                      // --- histogram (critical path) ---
    for (int i = threadIdx.x; i < NB; i += 256) h[i] = 0;
    __syncthreads();
    int start = b * EPB, end = start + EPB;
    for (int e = start + threadIdx.x; e < end; e += 256)
      atomicAdd(&h[dst[e] >> 8], 1);
    __syncthreads();
    for (int bb = threadIdx.x; bb < NB; bb += 256)
      cnt[bb * 256 + b] = h[bb];      // bucket-major layout
  } else if (b == 256) {              // --- weight split ---
    for (int i = threadIdx.x; i < DIN * DH; i += 256) {
      int k = i >> 6, n = i & 63;
      int kt = k >> 5, kin = k & 31;
      int lane = ((kin >> 3) << 4) | (n & 15);
      int j8 = kin & 7;
      int jt = n >> 4;
      float wl = W1l[i], wr = W1r[i];
      unsigned bl_ = __float_as_uint(wl);
      unsigned br_ = __float_as_uint(wr);
      short hl = (short)(bl_ >> 16);
      short hr = (short)(br_ >> 16);
      float rl = wl - __uint_as_float(bl_ & 0xFFFF0000u);
      float rr = wr - __uint_as_float(br_ & 0xFFFF0000u);
      short ll = (short)(__float_as_uint(rl) >> 16);
      short lr = (short)(__float_as_uint(rr) >> 16);
      int base0 = (((kt * 2 + 0) * 4 + jt) * 2) * 512 + lane * 8 + j8;
      int base1 = (((kt * 2 + 1) * 4 + jt) * 2) * 512 + lane * 8 + j8;
      wfrag[base0]       = hl;
      wfrag[base0 + 512] = ll;
      wfrag[base1]       = hr;
      wfrag[base1 + 512] = lr;
    }
  } else {                            // --- graph boundaries ---
    for (int g = threadIdx.x; g <= NG; g += 256) {
      if (g == NG) { gs[NG] = NN; continue; }
      int lo = 0, hi = NN;
      while (lo < hi) {
        int mid = (lo + hi) >> 1;
        if (batch[mid] < g) lo = mid + 1; else hi = mid;
      }
      gs[g] = lo;
    }
  }
}

// ---------- scan pass 1: per-block sums ----------
__global__ __launch_bounds__(256) void reduce_kernel(
    const int* __restrict__ cnt, int* __restrict__ partials) {
  __shared__ int s[256];
  int i = blockIdx.x * 256 + threadIdx.x;
  s[threadIdx.x] = cnt[i];
  __syncthreads();
  for (int off = 128; off > 0; off >>= 1) {
    if (threadIdx.x < off) s[threadIdx.x] += s[threadIdx.x + off];
    __syncthreads();
  }
  if (threadIdx.x == 0) partials[blockIdx.x] = s[0];
}

// ---------- scan pass 2: exclusive scan of NB partials (1 block) ----------
__global__ __launch_bounds__(256) void scanpart_kernel(int* __restrict__ partials) {
  __shared__ int s[NB];
  for (int i = threadIdx.x; i < NB; i += 256) s[i] = partials[i];
  __syncthreads();
  if (threadIdx.x == 0) {
    int run = 0;
    for (int i = 0; i < NB; ++i) { int v = s[i]; s[i] = run; run += v; }
  }
  __syncthreads();
  for (int i = threadIdx.x; i < NB; i += 256) partials[i] = s[i];
}

// ---------- scan pass 3: per-block exclusive scan + offset ----------
__global__ __launch_bounds__(256) void scanfinal_kernel(
    const int* __restrict__ cnt, const int* __restrict__ partials,
    int* __restrict__ scanned) {
  __shared__ int s[256];
  int t = threadIdx.x;
  int i = blockIdx.x * 256 + t;
  int c = cnt[i];
  s[t] = c;
  __syncthreads();
  for (int off = 1; off < 256; off <<= 1) {
    int v = (t >= off) ? s[t - off] : 0;
    __syncthreads();
    s[t] += v;
    __syncthreads();
  }
  scanned[i] = s[t] - c + partials[blockIdx.x];
}

// ---------- fused: partA (blocks 0..255, critical) + proj MFMA (256..1037) ----------
__global__ __launch_bounds__(256) void proj_part_kernel(
    const int* __restrict__ src, const int* __restrict__ dst,
    const int* __restrict__ scanned, int* __restrict__ part,
    const float* __restrict__ x, const short* __restrict__ wfrag,
    const float* __restrict__ b1, unsigned short* __restrict__ xlb,
    unsigned short* __restrict__ xrb) {
  __shared__ short sB[32768];   // 64 KB (partA reuses as int cursor array)
  if (blockIdx.x < 256) {
    // --- partA: partition packed edges into buckets ---
    int* cur = (int*)sB;
    for (int i = threadIdx.x; i < NB; i += 256)
      cur[i] = scanned[i * 256 + blockIdx.x];
    __syncthreads();
    int start = blockIdx.x * EPB, end = start + EPB;
    for (int e = start + threadIdx.x; e < end; e += 256) {
      int d = dst[e], s = src[e];
      int pos = atomicAdd(&cur[d >> 8], 1);
      part[pos] = ((d & 255) << 17) | s;
    }
    return;
  }
  // --- proj: xl(bf16)=x@W1l, xr(bf16)=x@W1r+b1 ---
  {
    const float4* wf4 = (const float4*)wfrag;
    float4* sB4 = (float4*)sB;
    for (int i = threadIdx.x; i < 4096; i += 256) sB4[i] = wf4[i];
  }
  __syncthreads();

  int wave = threadIdx.x >> 6;
  int lane = threadIdx.x & 63;
  int m = lane & 15, q = lane >> 4;
  int tpair = (blockIdx.x - 256) * 4 + wave;
  int tile0 = tpair * 2, tile1 = tile0 + 1;
  if (tile0 >= 6250) return;

  int r0 = tile0 * 16 + m;
  int r1 = tile1 * 16 + m; if (r1 > NN - 1) r1 = NN - 1;
  const float4* xa = (const float4*)x + (size_t)r0 * 32 + q * 2;
  const float4* xb = (const float4*)x + (size_t)r1 * 32 + q * 2;

  floatx4 acc0[8], acc1[8];
#pragma unroll
  for (int a = 0; a < 8; ++a) {
    acc0[a] = (floatx4){0.f, 0.f, 0.f, 0.f};
    acc1[a] = (floatx4){0.f, 0.f, 0.f, 0.f};
  }

#pragma unroll
  for (int kt = 0; kt < 4; ++kt) {
    float4 p0 = xa[kt * 8];
    float4 p1 = xa[kt * 8 + 1];
    float4 p2 = xb[kt * 8];
    float4 p3 = xb[kt * 8 + 1];
    float af0[8] = {p0.x, p0.y, p0.z, p0.w, p1.x, p1.y, p1.z, p1.w};
    float af1[8] = {p2.x, p2.y, p2.z, p2.w, p3.x, p3.y, p3.z, p3.w};
    short8 ah0, al0, ah1, al1;
#pragma unroll
    for (int e = 0; e < 8; ++e) {
      unsigned b0 = __float_as_uint(af0[e]);
      ah0[e] = (short)(b0 >> 16);
      float lo0 = af0[e] - __uint_as_float(b0 & 0xFFFF0000u);
      al0[e] = (short)(__float_as_uint(lo0) >> 16);
      unsigned b1_ = __float_as_uint(af1[e]);
      ah1[e] = (short)(b1_ >> 16);
      float lo1 = af1[e] - __uint_as_float(b1_ & 0xFFFF0000u);
      al1[e] = (short)(__float_as_uint(lo1) >> 16);
    }
#pragma unroll
    for (int mat = 0; mat < 2; ++mat) {
#pragma unroll
      for (int jt = 0; jt < 4; ++jt) {
        int unit = ((kt * 2 + mat) * 4 + jt) * 2;
        short8 bh = *(const short8*)(sB + unit * 512 + lane * 8);
        short8 bl = *(const short8*)(sB + (unit + 1) * 512 + lane * 8);
        floatx4 c0 = acc0[mat * 4 + jt];
        c0 = __builtin_amdgcn_mfma_f32_16x16x32_bf16(ah0, bh, c0, 0, 0, 0);
        c0 = __builtin_amdgcn_mfma_f32_16x16x32_bf16(ah0, bl, c0, 0, 0, 0);
        c0 = __builtin_amdgcn_mfma_f32_16x16x32_bf16(al0, bh, c0, 0, 0, 0);
        acc0[mat * 4 + jt] = c0;
        floatx4 c1 = acc1[mat * 4 + jt];
        c1 = __builtin_amdgcn_mfma_f32_16x16x32_bf16(ah1, bh, c1, 0, 0, 0);
        c1 = __builtin_amdgcn_mfma_f32_16x16x32_bf16(ah1, bl, c1, 0, 0, 0);
        c1 = __builtin_amdgcn_mfma_f32_16x16x32_bf16(al1, bh, c1, 0, 0, 0);
        acc1[mat * 4 + jt] = c1;
      }
    }
  }

#pragma unroll
  for (int jt = 0; jt < 4; ++jt) {
    int j = jt * 16 + m;
    float bj = b1[j];
    floatx4 cl0 = acc0[jt], cr0 = acc0[4 + jt];
    floatx4 cl1 = acc1[jt], cr1 = acc1[4 + jt];
#pragma unroll
    for (int r = 0; r < 4; ++r) {
      int n0 = tile0 * 16 + q * 4 + r;
      xlb[(size_t)n0 * DH + j] = f2bf(cl0[r]);
      xrb[(size_t)n0 * DH + j] = f2bf(cr0[r] + bj);
    }
    if (tile1 < 6250) {
#pragma unroll
      for (int r = 0; r < 4; ++r) {
        int n1 = tile1 * 16 + q * 4 + r;
        xlb[(size_t)n1 * DH + j] = f2bf(cl1[r]);
        xrb[(size_t)n1 * DH + j] = f2bf(cr1[r] + bj);
      }
    }
  }
}

// ---------- radix pass B: per-bucket CSR (row_start + eidx) ----------
__global__ __launch_bounds__(256) void bucket_csr_kernel(
    const int* __restrict__ part, const int* __restrict__ scanned,
    int* __restrict__ row_start, int* __restrict__ eidx) {
  int b = blockIdx.x, t = threadIdx.x;
  int ebeg = scanned[b * 256];
  int eend = (b == NB - 1) ? NE : scanned[(b + 1) * 256];
  int nbase = b << 8;
  int nloc = NN - nbase; if (nloc > 256) nloc = 256;
  __shared__ int cntL[256];
  __shared__ int exclL[256];
  cntL[t] = 0;
  __syncthreads();
  for (int e = ebeg + t; e < eend; e += 256)
    atomicAdd(&cntL[part[e] >> 17], 1);
  __syncthreads();
  int c = cntL[t];
  exclL[t] = c;
  __syncthreads();
  for (int off = 1; off < 256; off <<= 1) {
    int v = (t >= off) ? exclL[t - off] : 0;
    __syncthreads();
    exclL[t] += v;
    __syncthreads();
  }
  int excl = exclL[t] - c;
  if (t < nloc) row_start[nbase + t] = ebeg + excl;
  if (b == NB - 1 && t == 0) row_start[NN] = NE;
  cntL[t] = excl;                 // reuse as cursor
  __syncthreads();
  for (int e = ebeg + t; e < eend; e += 256) {
    int v = part[e];
    int pos = atomicAdd(&cntL[v >> 17], 1);
    eidx[ebeg + pos] = v & 0x1FFFF;
  }
}

// ---------- mean aggregation via gather (bf16 rows, 8 lanes x uint4/node) ----------
template <bool RELU_ADD>
__global__ __launch_bounds__(256) void gather_kernel(
    const uint4* __restrict__ feat4, const int* __restrict__ row_start,
    const int* __restrict__ eidx, const uint4* __restrict__ xr4,
    uint4* __restrict__ out4) {
  int t = blockIdx.x * 256 + threadIdx.x;
  int node = t >> 3;
  if (node >= NN) return;
  int fl = t & 7;
  int rs = row_start[node], re = row_start[node + 1];
  float a0 = 0.f, a1 = 0.f, a2 = 0.f, a3 = 0.f;
  float a4 = 0.f, a5 = 0.f, a6 = 0.f, a7 = 0.f;
  int k = rs;
  for (; k + 8 <= re; k += 8) {           // 8 uint4 loads in flight
    uint4 v[8];
#pragma unroll
    for (int u = 0; u < 8; ++u) v[u] = feat4[(size_t)eidx[k + u] * 8 + fl];
#pragma unroll
    for (int u = 0; u < 8; ++u) {
      a0 += bflo(v[u].x); a1 += bfhi(v[u].x);
      a2 += bflo(v[u].y); a3 += bfhi(v[u].y);
      a4 += bflo(v[u].z); a5 += bfhi(v[u].z);
      a6 += bflo(v[u].w); a7 += bfhi(v[u].w);
    }
  }
  for (; k + 2 <= re; k += 2) {
    uint4 v0 = feat4[(size_t)eidx[k] * 8 + fl];
    uint4 v1 = feat4[(size_t)eidx[k + 1] * 8 + fl];
    a0 += bflo(v0.x) + bflo(v1.x); a1 += bfhi(v0.x) + bfhi(v1.x);
    a2 += bflo(v0.y) + bflo(v1.y); a3 += bfhi(v0.y) + bfhi(v1.y);
    a4 += bflo(v0.z) + bflo(v1.z); a5 += bfhi(v0.z) + bfhi(v1.z);
    a6 += bflo(v0.w) + bflo(v1.w); a7 += bfhi(v0.w) + bfhi(v1.w);
  }
  if (k < re) {
    uint4 v = feat4[(size_t)eidx[k] * 8 + fl];
    a0 += bflo(v.x); a1 += bfhi(v.x);
    a2 += bflo(v.y); a3 += bfhi(v.y);
    a4 += bflo(v.z); a5 += bfhi(v.z);
    a6 += bflo(v.w); a7 += bfhi(v.w);
  }
  float inv = 1.0f / fmaxf((float)(re - rs), 1.0f);
  a0 *= inv; a1 *= inv; a2 *= inv; a3 *= inv;
  a4 *= inv; a5 *= inv; a6 *= inv; a7 *= inv;
  if (RELU_ADD) {
    uint4 r = xr4[(size_t)node * 8 + fl];
    a0 = fmaxf(a0 + bflo(r.x), 0.f); a1 = fmaxf(a1 + bfhi(r.x), 0.f);
    a2 = fmaxf(a2 + bflo(r.y), 0.f); a3 = fmaxf(a3 + bfhi(r.y), 0.f);
    a4 = fmaxf(a4 + bflo(r.z), 0.f); a5 = fmaxf(a5 + bfhi(r.z), 0.f);
    a6 = fmaxf(a6 + bflo(r.w), 0.f); a7 = fmaxf(a7 + bfhi(r.w), 0.f);
  }
  uint4 o;
  o.x = pack2(a0, a1);
  o.y = pack2(a2, a3);
  o.z = pack2(a4, a5);
  o.w = pack2(a6, a7);
  out4[(size_t)node * 8 + fl] = o;
}

// ---------- fused pool + final matmul: one block per graph ----------
__global__ __launch_bounds__(256) void pool_final_kernel(
    const unsigned* __restrict__ hb2, const unsigned* __restrict__ mb2,
    const int* __restrict__ gs, const float* __restrict__ W2l,
    const float* __restrict__ W2r, const float* __restrict__ b2,
    float* __restrict__ out) {
  int g = blockIdx.x;
  int start = gs[g], end = gs[g + 1];
  int slot = threadIdx.x >> 5;        // 0..7
  int j2   = threadIdx.x & 31;        // uint index (2 feats)
  float sh0 = 0.f, sh1 = 0.f, sm0 = 0.f, sm1 = 0.f;
  for (int n = start + slot; n < end; n += 8) {
    unsigned hv = hb2[(size_t)n * 32 + j2];
    unsigned mv = mb2[(size_t)n * 32 + j2];
    sh0 += bflo(hv); sh1 += bfhi(hv);
    sm0 += bflo(mv); sm1 += bfhi(mv);
  }
  __shared__ float redh[8][DH];
  __shared__ float redm[8][DH];
  redh[slot][j2 * 2] = sh0; redh[slot][j2 * 2 + 1] = sh1;
  redm[slot][j2 * 2] = sm0; redm[slot][j2 * 2 + 1] = sm1;
  __syncthreads();
  __shared__ float hsL[DH], msL[DH];
  if (threadIdx.x < DH) {
    float a = 0.f, b = 0.f;
#pragma unroll
    for (int s = 0; s < 8; ++s) { a += redh[s][threadIdx.x]; b += redm[s][threadIdx.x]; }
    hsL[threadIdx.x] = a; msL[threadIdx.x] = b;
  }
  __syncthreads();
  int j = threadIdx.x;
  if (j < DOUT) {
    float n = (float)(end - start);
    float acc = 0.f;
#pragma unroll 8
    for (int k = 0; k < DH; ++k)
      acc += msL[k] * W2l[k * DOUT + j] + hsL[k] * W2r[k * DOUT + j];
    out[g * DOUT + j] = (acc + n * b2[j]) / fmaxf(n, 1.0f);
  }
}

extern "C" void kernel_launch(void* const* d_in, const int* in_sizes, int n_in,
                              void* d_out, int out_size, void* d_ws, size_t ws_size,
                              hipStream_t stream) {
  (void)in_sizes; (void)n_in; (void)out_size; (void)ws_size;
  const float* x   = (const float*)d_in[0];
  const float* W1l = (const float*)d_in[1];
  const float* W1r = (const float*)d_in[2];
  const float* b1  = (const float*)d_in[3];
  const float* W2l = (const float*)d_in[4];
  const float* W2r = (const float*)d_in[5];
  const float* b2  = (const float*)d_in[6];
  const int*   ei  = (const int*)d_in[7];
  const int*   batch = (const int*)d_in[8];
  const int* src = ei;            // edge_index[0, :]
  const int* dst = ei + NE;       // edge_index[1, :]
  float* out = (float*)d_out;

  char* ws = (char*)d_ws;
  unsigned short* xlb = (unsigned short*)(ws);            // 12,800,000 B
  unsigned short* hb  = (unsigned short*)(ws + 12800000); // 12,800,000 B
  unsigned short* mb  = (unsigned short*)(ws + 25600000); // 12,800,000 B
  unsigned short* xrb = (unsigned short*)(ws + 38400000); // 12,800,000 B
  int*  part      = (int*)(ws + 51200000);           //  6,400,000 B
  int*  cnt       = (int*)(ws + 57600000);           //    400,384 B (MSZ)
  int*  scanned   = (int*)(ws + 58000384);           //    400,384 B (MSZ)
  int*  eidx      = (int*)(ws + 76800000);           //  6,400,000 B
  int*  row_start = (int*)(ws + 83200000);           //    400,004 B
  int*   gs       = (int*)(ws + 83600128);           //      2,052 B
  short* wfrag    = (short*)(ws + 83900032);         //     65,536 B
  int*  partials  = (int*)(ws + 84400128);           //      1,564 B

  const int gBlocks = (NN * 8 + 255) / 256;          // 3125

  // prep: histogram + weight split + graph bounds (fused, independent roles)
  prep_kernel<<<258, 256, 0, stream>>>(dst, cnt, W1l, W1r, wfrag, batch, gs);
  reduce_kernel<<<NB, 256, 0, stream>>>(cnt, partials);
  scanpart_kernel<<<1, 256, 0, stream>>>(partials);
  scanfinal_kernel<<<NB, 256, 0, stream>>>(cnt, partials, scanned);

  // partA (critical path) + proj MFMA (independent) fused
  proj_part_kernel<<<1038, 256, 0, stream>>>(src, dst, scanned, part,
                                             x, wfrag, b1, xlb, xrb);
  bucket_csr_kernel<<<NB, 256, 0, stream>>>(part, scanned, row_start, eidx);

  // layer 1 aggregation (+ relu + root add)
  gather_kernel<true><<<gBlocks, 256, 0, stream>>>(
      (const uint4*)xlb, row_start, eidx, (const uint4*)xrb, (uint4*)hb);

  // layer 2 aggregation
  gather_kernel<false><<<gBlocks, 256, 0, stream>>>(
      (const uint4*)hb, row_start, eidx, nullptr, (uint4*)mb);

  // fused pool + final matmul
  pool_final_kernel<<<NG, 256, 0, stream>>>(
      (const unsigned*)hb, (const unsigned*)mb, gs, W2l, W2r, b2, out);
}